// Round 4
// baseline (682.975 us; speedup 1.0000x reference)
//
#include <hip/hip_runtime.h>

// ---------------------------------------------------------------------------
// SDGL gcn_module: out = W1*x + W2*(G1 x) + W3*(G2 x) + b
//   G1 = AL^2 + AS - AS*AL ; G2 = AL^3 + AS^2 - AS2*AL   (per-slice linear op)
// KEY: channel-mix (over c) commutes with graph ops (over n):
//   W2*(G1 x) = G1*(W2 x).  Mix FIRST (K=32 MFMA, one pass over x), then one
//   fused graph GEMM (K=2048), epilogue out = V + Y0 + bias.
// R4: (a) Yc3[j][3072] = [W1x|W2x|W3x] — single mix output, all 16B vector
//     stores; blocks own 32n x 32t x 32o slabs so 128B lines complete within
//     a block(+nc neighbor, same XCD) and merge in L2 (R3 write-amp 2.7x).
//     (b) GEMM epilogue reads Y0 as ushort4 (was 128 scalar bf16 loads).
//     (c) pre-GEMMs 6 -> 5 (AL3 = AL2*AL, drop AL2t).
// ---------------------------------------------------------------------------

typedef __bf16 bf16x8 __attribute__((ext_vector_type(8)));
typedef float f32x4 __attribute__((ext_vector_type(4)));
typedef unsigned int u32x4 __attribute__((ext_vector_type(4)));
typedef unsigned int u32x2 __attribute__((ext_vector_type(2)));

__device__ __forceinline__ unsigned short f2bf(float f) {
  unsigned u = __builtin_bit_cast(unsigned, f);
  u += 0x7fffu + ((u >> 16) & 1u);           // round-to-nearest-even
  return (unsigned short)(u >> 16);
}
__device__ __forceinline__ float bf2f(unsigned short h) {
  unsigned u = ((unsigned)h) << 16;
  return __builtin_bit_cast(float, u);
}

// ---------------- workspace layout (bytes) ----------------
static constexpr size_t OFF_YC    = 0;                      // 32768*3072*2 = 192 MiB
static constexpr size_t OFF_ALBF  = 201326592;              // each small mat 2 MiB
static constexpr size_t OFF_ALT   = OFF_ALBF  + 2097152;
static constexpr size_t OFF_ASBF  = OFF_ALT   + 2097152;
static constexpr size_t OFF_AST   = OFF_ASBF  + 2097152;
static constexpr size_t OFF_AL2   = OFF_AST   + 2097152;
static constexpr size_t OFF_AL2T  = OFF_AL2   + 2097152;    // unused (layout keep)
static constexpr size_t OFF_ASAL  = OFF_AL2T  + 2097152;
static constexpr size_t OFF_AS2   = OFF_ASAL  + 2097152;
static constexpr size_t OFF_AL3   = OFF_AS2   + 2097152;
static constexpr size_t OFF_AS2AL = OFF_AL3   + 2097152;
static constexpr size_t OFF_G     = OFF_AS2AL + 2097152;    // 1024*2048*2 = 4 MiB
// Wall (96x32 bf16, 6 KiB) reuses OFF_ALBF after stage0 retires ALbf.

// ---------------- simple fp32 -> bf16 cast ----------------
__global__ __launch_bounds__(256) void k_cast_bf16(const float* __restrict__ src,
                                                   unsigned short* __restrict__ dst,
                                                   int n4) {
  int i = blockIdx.x * 256 + threadIdx.x;
  if (i < n4) {
    float4 v = *((const float4*)src + i);
    unsigned lo = (unsigned)f2bf(v.x) | ((unsigned)f2bf(v.y) << 16);
    unsigned hi = (unsigned)f2bf(v.z) | ((unsigned)f2bf(v.w) << 16);
    u32x2 pk = {lo, hi};
    *(u32x2*)(dst + (size_t)i * 4) = pk;
  }
}

// ---------------- Wall[g*32+o][c] = W[o][g*32+c] bf16 ----------------
__global__ __launch_bounds__(256) void k_cast_wall(const float* __restrict__ W,
                                                   unsigned short* __restrict__ Wall) {
  int i = blockIdx.x * 256 + threadIdx.x;   // 3072
  if (i < 3072) {
    int oo = i >> 5, c = i & 31;
    int o = oo & 31, g = oo >> 5;
    Wall[i] = f2bf(W[o * 96 + g * 32 + c]);
  }
}

// ---------------- 64x64 tiled transpose + cast (AL/AS only) ----------------
__global__ __launch_bounds__(256) void k_transpose_cast(const float* __restrict__ src,
                                                        unsigned short* __restrict__ dst,
                                                        int R, int Cc) {
  __shared__ float Xs[64][65];
  const int tid = threadIdx.x;
  const size_t slice = (size_t)blockIdx.z * (size_t)R * (size_t)Cc;
  const float* s = src + slice;
  unsigned short* d = dst + slice;
  const int r0 = blockIdx.x * 64, c0 = blockIdx.y * 64;
  const int lrow = tid >> 4, lc4 = tid & 15;
#pragma unroll
  for (int rr = 0; rr < 4; rr++) {
    int row = rr * 16 + lrow;
    float4 v = *(const float4*)(s + (size_t)(r0 + row) * Cc + c0 + lc4 * 4);
    Xs[row][lc4 * 4 + 0] = v.x;
    Xs[row][lc4 * 4 + 1] = v.y;
    Xs[row][lc4 * 4 + 2] = v.z;
    Xs[row][lc4 * 4 + 3] = v.w;
  }
  __syncthreads();
  const int wc = tid & 7;
#pragma unroll
  for (int u = 0; u < 2; u++) {
    int t = u * 32 + (tid >> 3);
    unsigned v0 = (unsigned)f2bf(Xs[wc * 8 + 0][t]) | ((unsigned)f2bf(Xs[wc * 8 + 1][t]) << 16);
    unsigned v1 = (unsigned)f2bf(Xs[wc * 8 + 2][t]) | ((unsigned)f2bf(Xs[wc * 8 + 3][t]) << 16);
    unsigned v2 = (unsigned)f2bf(Xs[wc * 8 + 4][t]) | ((unsigned)f2bf(Xs[wc * 8 + 5][t]) << 16);
    unsigned v3 = (unsigned)f2bf(Xs[wc * 8 + 6][t]) | ((unsigned)f2bf(Xs[wc * 8 + 7][t]) << 16);
    u32x4 pk = {v0, v1, v2, v3};
    *(u32x4*)(d + (size_t)(c0 + t) * R + r0 + wc * 8) = pk;
  }
}

// ---------------- core 128x128 bf16 GEMM, C = A * Bt^T (pre-GEMMs) ----------
__device__ __forceinline__ void gemm128_bt(const unsigned short* __restrict__ A,
                                           const unsigned short* __restrict__ Bt,
                                           unsigned short* __restrict__ Cp,
                                           int K, size_t ldc, int m0, int n0) {
  __shared__ unsigned short As[128 * 32];
  __shared__ unsigned short Bs[128 * 32];
  const int tid = threadIdx.x;
  const int wave = tid >> 6, lane = tid & 63;
  const int lane15 = lane & 15, quad = lane >> 4;
  const int wm = wave & 1, wn = wave >> 1;
  const int srow = lane >> 2;
  const int schunk = (lane & 3) * 8;

  const unsigned short* gA0 = A + (size_t)(m0 + wave * 16 + srow) * K + schunk;
  const unsigned short* gA1 = A + (size_t)(m0 + 64 + wave * 16 + srow) * K + schunk;
  const unsigned short* gB0 = Bt + (size_t)(n0 + wave * 16 + srow) * K + schunk;
  const unsigned short* gB1 = Bt + (size_t)(n0 + 64 + wave * 16 + srow) * K + schunk;
  unsigned short* lA0 = As + (wave * 16) * 32;
  unsigned short* lA1 = As + (64 + wave * 16) * 32;
  unsigned short* lB0 = Bs + (wave * 16) * 32;
  unsigned short* lB1 = Bs + (64 + wave * 16) * 32;

  f32x4 acc[4][4];
#pragma unroll
  for (int i = 0; i < 4; i++)
#pragma unroll
    for (int j = 0; j < 4; j++) acc[i][j] = (f32x4){0.f, 0.f, 0.f, 0.f};

  const unsigned short* pa = As + (wm * 64 + lane15) * 32 + quad * 8;
  const unsigned short* pb = Bs + (wn * 64 + lane15) * 32 + quad * 8;

  for (int kb = 0; kb < K; kb += 32) {
    __syncthreads();
    __builtin_amdgcn_global_load_lds(
        (const __attribute__((address_space(1))) unsigned int*)(gA0 + kb),
        (__attribute__((address_space(3))) unsigned int*)lA0, 16, 0, 0);
    __builtin_amdgcn_global_load_lds(
        (const __attribute__((address_space(1))) unsigned int*)(gA1 + kb),
        (__attribute__((address_space(3))) unsigned int*)lA1, 16, 0, 0);
    __builtin_amdgcn_global_load_lds(
        (const __attribute__((address_space(1))) unsigned int*)(gB0 + kb),
        (__attribute__((address_space(3))) unsigned int*)lB0, 16, 0, 0);
    __builtin_amdgcn_global_load_lds(
        (const __attribute__((address_space(1))) unsigned int*)(gB1 + kb),
        (__attribute__((address_space(3))) unsigned int*)lB1, 16, 0, 0);
    __syncthreads();

    bf16x8 av[4], bv[4];
#pragma unroll
    for (int mt = 0; mt < 4; mt++) av[mt] = *(const bf16x8*)(pa + mt * 16 * 32);
#pragma unroll
    for (int nt = 0; nt < 4; nt++) bv[nt] = *(const bf16x8*)(pb + nt * 16 * 32);
#pragma unroll
    for (int mt = 0; mt < 4; mt++)
#pragma unroll
      for (int nt = 0; nt < 4; nt++)
        acc[mt][nt] = __builtin_amdgcn_mfma_f32_16x16x32_bf16(av[mt], bv[nt], acc[mt][nt], 0, 0, 0);
  }

#pragma unroll
  for (int mt = 0; mt < 4; mt++) {
#pragma unroll
    for (int nt = 0; nt < 4; nt++) {
      const int col = n0 + wn * 64 + nt * 16 + lane15;
#pragma unroll
      for (int r = 0; r < 4; r++) {
        const int row = m0 + wm * 64 + mt * 16 + quad * 4 + r;
        Cp[(size_t)row * ldc + col] = f2bf(acc[mt][nt][r]);
      }
    }
  }
}

// ---------------- G-precompute GEMMs (batched by z; 5 total) ----------------
__global__ __launch_bounds__(256) void k_gemm_pre(char* ws, int stage) {
  const unsigned short* A;
  const unsigned short* Bt;
  unsigned short* Cp;
  const int z = blockIdx.z;
  unsigned short* ALbf = (unsigned short*)(ws + OFF_ALBF);
  unsigned short* ALt  = (unsigned short*)(ws + OFF_ALT);
  unsigned short* ASbf = (unsigned short*)(ws + OFF_ASBF);
  unsigned short* ASt  = (unsigned short*)(ws + OFF_AST);
  unsigned short* AL2  = (unsigned short*)(ws + OFF_AL2);
  unsigned short* ASAL = (unsigned short*)(ws + OFF_ASAL);
  unsigned short* AS2  = (unsigned short*)(ws + OFF_AS2);
  unsigned short* AL3  = (unsigned short*)(ws + OFF_AL3);
  unsigned short* AS2AL= (unsigned short*)(ws + OFF_AS2AL);
  if (stage == 0) {
    if (z == 0)      { A = ALbf; Bt = ALt;  Cp = AL2;  }   // AL^2
    else if (z == 1) { A = ASbf; Bt = ALt;  Cp = ASAL; }   // AS*AL
    else             { A = ASbf; Bt = ASt;  Cp = AS2;  }   // AS^2
  } else {
    if (z == 0)      { A = AL2;  Bt = ALt;  Cp = AL3;  }   // AL^2*AL = AL^3
    else             { A = AS2;  Bt = ALt;  Cp = AS2AL;}   // AS^2*AL
  }
  gemm128_bt(A, Bt, Cp, 1024, 1024, blockIdx.y * 128, blockIdx.x * 128);
}

// ---------------- assemble Gcat[1024][2048] = [G1 | G2] bf16 ----------------
__global__ __launch_bounds__(256) void k_assemble_G(const unsigned short* __restrict__ AL2,
                                                    const unsigned short* __restrict__ ASAL,
                                                    const float* __restrict__ ASf,
                                                    const unsigned short* __restrict__ AL3,
                                                    const unsigned short* __restrict__ AS2,
                                                    const unsigned short* __restrict__ AS2AL,
                                                    unsigned short* __restrict__ G) {
  int i = blockIdx.x * 256 + threadIdx.x;           // over 1024*1024
  int r = i >> 10, c = i & 1023;
  float g1 = bf2f(AL2[i]) + ASf[i] - bf2f(ASAL[i]);
  float g2 = bf2f(AL3[i]) + bf2f(AS2[i]) - bf2f(AS2AL[i]);
  G[(size_t)r * 2048 + c]        = f2bf(g1);
  G[(size_t)r * 2048 + 1024 + c] = f2bf(g2);
}

// ---------------- k_mix_g: channel mix via MFMA (K=32) ----------------
// R4: single output Yc3[j=(b,o,t)][3072] = [W1x | W2x | W3x], rows 6144B.
// grid 1024 = 16 b x 32 nc(32 n) x 2 th(32 t); 256 thr = 4 waves =
// (nh 0..1: 16 n) x (tq' 0..1: 16 t).  Per wave loop ng 0..1 over 8 n.
// A 128B line of Yc3 (64 n) is covered by this block (32 n) + the adjacent
// nc block (same XCD via chunked decode) -> L2 merge, no write-amp.
// Per-wave MFMA: B-frags = x[b, c, n, t=lane15-based] (64B segments),
// A-frags = Wall rows.  D: col=lane15->t, row=quad*4+r->o.
__global__ __launch_bounds__(256, 4) void k_mix_g(const float* __restrict__ x,
                                                  const unsigned short* __restrict__ Wall,
                                                  unsigned short* __restrict__ Yc) {
  const int tid = threadIdx.x;
  // XCD chunking: XCD k owns sid in [k*128, (k+1)*128)
  const int sid = (blockIdx.x & 7) * 128 + (blockIdx.x >> 3);
  const int b   = sid >> 6;
  const int nc  = (sid >> 1) & 31;
  const int th  = sid & 1;
  const int wave = tid >> 6, lane = tid & 63;
  const int lane15 = lane & 15, quad = lane >> 4;
  const int nh = wave >> 1;
  const int tq = th * 2 + (wave & 1);
  const int t  = tq * 16 + lane15;

  // A-frags: Wall[96][32] bf16, row = ot*16+lane15, k-chunk = quad*8
  bf16x8 afr[6];
#pragma unroll
  for (int ot = 0; ot < 6; ot++)
    afr[ot] = *(const bf16x8*)(Wall + (ot * 16 + lane15) * 32 + quad * 8);

  const float* xb = x + (size_t)b * 2097152 + (size_t)(quad * 8) * 65536 + t;

#pragma unroll
  for (int ng = 0; ng < 2; ng++) {
    const int n8 = nc * 32 + nh * 16 + ng * 8;
    bf16x8 bfr[8];
#pragma unroll
    for (int nl = 0; nl < 8; nl++) {
      const float* xp = xb + (size_t)(n8 + nl) * 64;
      unsigned u[4];
#pragma unroll
      for (int e = 0; e < 4; e++) {
        float a  = xp[(size_t)(2 * e) * 65536];
        float c2 = xp[(size_t)(2 * e + 1) * 65536];
        u[e] = (unsigned)f2bf(a) | ((unsigned)f2bf(c2) << 16);
      }
      u32x4 pk = {u[0], u[1], u[2], u[3]};
      bfr[nl] = __builtin_bit_cast(bf16x8, pk);
    }

#pragma unroll
    for (int ot = 0; ot < 6; ot++) {
      f32x4 acc[8];
      const f32x4 z = (f32x4){0.f, 0.f, 0.f, 0.f};
#pragma unroll
      for (int nl = 0; nl < 8; nl++)
        acc[nl] = __builtin_amdgcn_mfma_f32_16x16x32_bf16(afr[ot], bfr[nl], z, 0, 0, 0);
      const int og = ot >> 1;                       // 0:W1x 1:W2x 2:W3x
      const int o  = (ot & 1) * 16 + quad * 4;      // + r
#pragma unroll
      for (int r = 0; r < 4; r++) {
        unsigned u0 = (unsigned)f2bf(acc[0][r]) | ((unsigned)f2bf(acc[1][r]) << 16);
        unsigned u1 = (unsigned)f2bf(acc[2][r]) | ((unsigned)f2bf(acc[3][r]) << 16);
        unsigned u2 = (unsigned)f2bf(acc[4][r]) | ((unsigned)f2bf(acc[5][r]) << 16);
        unsigned u3 = (unsigned)f2bf(acc[6][r]) | ((unsigned)f2bf(acc[7][r]) << 16);
        u32x4 pk = {u0, u1, u2, u3};
        size_t row = (size_t)(b * 32 + o + r) * 64 + t;
        *(u32x4*)(Yc + row * 3072 + og * 1024 + n8) = pk;
      }
    }
  }
}

// ---------------- main GEMM: out = Gcat @ [W2x|W3x]^T + W1x + bias ----------
// M=1024, N=32768, K=2048 (32 K-tiles of BK=64). 512 blocks x 512 thr.
// B-operand = Yc3 cols [1024..3072) (rows 3072-short stride); epilogue reads
// W1x as ushort4 from Yc3 cols [0..1024).  8 waves (2M x 4N); per-wave
// C = 128x64. LDS 128 KiB dbuf; row-XOR swizzle; counted vmcnt(6); setprio.
__global__ __launch_bounds__(512) void k_gemm_main8(const unsigned short* __restrict__ A,
                                                    const unsigned short* __restrict__ Yc,
                                                    const float* __restrict__ bm,
                                                    float* __restrict__ out) {
  __shared__ unsigned short lds[65536];   // 128 KiB
  const unsigned short* Bt = Yc + 1024;   // k=0 <-> col 1024
  const int tid = threadIdx.x;
  const int wave = tid >> 6, lane = tid & 63;
  const int lane15 = lane & 15, quad = lane >> 4;
  const int wr = wave >> 2, wc = wave & 3;          // 2M x 4N

  // XCD-aware bijective swizzle: nwg=512, 8 XCDs, cpx=64.
  const int bid = blockIdx.x;
  const int swz = (bid & 7) * 64 + (bid >> 3);
  const int nx = swz >> 2, my = swz & 3;            // 128 N-tiles x 4 M-tiles
  const int m0 = my * 256, n0 = nx * 256;

  const int srow = tid >> 3;                          // 0..63
  const int skc  = (((tid & 7) ^ (srow & 7)) << 3);   // shorts
  const int ldst0 = (tid & ~63) << 3;                 // shorts, wave-uniform

#define STAGE_HALF(gbase, rowbase, ldsptr, ktile, gstr)                                 \
  do {                                                                                  \
    const unsigned short* _g =                                                          \
        (gbase) + (size_t)((rowbase) + srow) * (gstr) + (size_t)((ktile) * 64 + skc);   \
    __builtin_amdgcn_global_load_lds(                                                   \
        (const __attribute__((address_space(1))) unsigned int*)_g,                      \
        (__attribute__((address_space(3))) unsigned int*)((ldsptr) + ldst0), 16, 0, 0); \
    __builtin_amdgcn_global_load_lds(                                                   \
        (const __attribute__((address_space(1))) unsigned int*)(_g + 64 * (size_t)(gstr)),\
        (__attribute__((address_space(3))) unsigned int*)((ldsptr) + 4096 + ldst0),     \
        16, 0, 0);                                                                      \
  } while (0)

#define LOAD_AFR(p)                                                                     \
  bf16x8 afr[2][2];                                                                     \
  _Pragma("unroll") for (int mi = 0; mi < 2; mi++)                                      \
      _Pragma("unroll") for (int kk = 0; kk < 2; kk++)                                  \
          afr[mi][kk] = *(const bf16x8*)(pA + (2 * (p) + mi) * 1024 + aks[kk]);

#define MFMA_QUAD(p)                                                                    \
  _Pragma("unroll") for (int kk = 0; kk < 2; kk++)                                      \
      _Pragma("unroll") for (int mi = 0; mi < 2; mi++)                                  \
          _Pragma("unroll") for (int n = 0; n < 4; n++)                                 \
              acc[2 * (p) + mi][n] = __builtin_amdgcn_mfma_f32_16x16x32_bf16(           \
                  afr[mi][kk], bfr[n][kk], acc[2 * (p) + mi][n], 0, 0, 0);

#define PHASE_SYNC_PRE()                              \
  asm volatile("" ::: "memory");                      \
  __builtin_amdgcn_s_barrier();                       \
  asm volatile("s_waitcnt lgkmcnt(0)" ::: "memory");  \
  __builtin_amdgcn_sched_barrier(0);                  \
  __builtin_amdgcn_s_setprio(1);

#define PHASE_SYNC_POST()                             \
  __builtin_amdgcn_s_setprio(0);                      \
  asm volatile("" ::: "memory");                      \
  __builtin_amdgcn_s_barrier();

  unsigned short* Acur = lds;
  unsigned short* Bcur = lds + 16384;
  unsigned short* Aalt = lds + 32768;
  unsigned short* Balt = lds + 49152;

  f32x4 acc[8][4];
#pragma unroll
  for (int i = 0; i < 8; i++)
#pragma unroll
    for (int j = 0; j < 4; j++) acc[i][j] = (f32x4){0.f, 0.f, 0.f, 0.f};

  const int swz8 = (lane15 & 7) << 3;
  int aks[2];
  aks[0] = (quad << 3) ^ swz8;
  aks[1] = (32 | (quad << 3)) ^ swz8;

  // ---- prologue: tile0 fully + tile1 {B0,B1,A0}; vmcnt(6) => tile0 landed ----
  STAGE_HALF(Bt, n0,       Bcur,        0, 3072);
  STAGE_HALF(Bt, n0 + 128, Bcur + 8192, 0, 3072);
  STAGE_HALF(A,  m0,       Acur,        0, 2048);
  STAGE_HALF(A,  m0 + 128, Acur + 8192, 0, 2048);
  STAGE_HALF(Bt, n0,       Balt,        1, 3072);
  STAGE_HALF(Bt, n0 + 128, Balt + 8192, 1, 3072);
  STAGE_HALF(A,  m0,       Aalt,        1, 2048);
  asm volatile("s_waitcnt vmcnt(6)" ::: "memory");
  __builtin_amdgcn_s_barrier();

  // ---- main loop: tiles 0..29 with full staging ----
  for (int u = 0; u < 30; ++u) {
    const unsigned short* pA = Acur + (wr * 128 + lane15) * 64;
    const unsigned short* pB = Bcur + (wc * 64 + lane15) * 64;
    bf16x8 bfr[4][2];
    {   // phase 0: B frags (8) + A quad 0; stage A1(u+1) -> alt
#pragma unroll
      for (int n = 0; n < 4; n++)
#pragma unroll
        for (int kk = 0; kk < 2; kk++)
          bfr[n][kk] = *(const bf16x8*)(pB + n * 1024 + aks[kk]);
      LOAD_AFR(0)
      __builtin_amdgcn_sched_barrier(0);
      STAGE_HALF(A, m0 + 128, Aalt + 8192, u + 1, 2048);
      asm volatile("s_waitcnt lgkmcnt(8)" ::: "memory");
      PHASE_SYNC_PRE()
      MFMA_QUAD(0)
      PHASE_SYNC_POST()
    }
    {   // phase 1: stage B0(u+2) -> cur (B(u) reads retired at p0)
      LOAD_AFR(1)
      __builtin_amdgcn_sched_barrier(0);
      STAGE_HALF(Bt, n0, Bcur, u + 2, 3072);
      PHASE_SYNC_PRE()
      MFMA_QUAD(1)
      PHASE_SYNC_POST()
    }
    {   // phase 2: stage B1(u+2) -> cur
      LOAD_AFR(2)
      __builtin_amdgcn_sched_barrier(0);
      STAGE_HALF(Bt, n0 + 128, Bcur + 8192, u + 2, 3072);
      PHASE_SYNC_PRE()
      MFMA_QUAD(2)
      PHASE_SYNC_POST()
    }
    {   // phase 3: stage A0(u+2) -> cur ; counted vmcnt(6) => tile u+1 complete
      LOAD_AFR(3)
      __builtin_amdgcn_sched_barrier(0);
      STAGE_HALF(A, m0, Acur, u + 2, 2048);
      PHASE_SYNC_PRE()
      MFMA_QUAD(3)
      __builtin_amdgcn_s_setprio(0);
      asm volatile("s_waitcnt vmcnt(6)" ::: "memory");
      asm volatile("" ::: "memory");
      __builtin_amdgcn_s_barrier();
    }
    unsigned short* t;
    t = Acur; Acur = Aalt; Aalt = t;
    t = Bcur; Bcur = Balt; Balt = t;
  }

  // ---- tile 30: last stage (A1 of tile 31), then full drain ----
  {
    const unsigned short* pA = Acur + (wr * 128 + lane15) * 64;
    const unsigned short* pB = Bcur + (wc * 64 + lane15) * 64;
    bf16x8 bfr[4][2];
    {
#pragma unroll
      for (int n = 0; n < 4; n++)
#pragma unroll
        for (int kk = 0; kk < 2; kk++)
          bfr[n][kk] = *(const bf16x8*)(pB + n * 1024 + aks[kk]);
      LOAD_AFR(0)
      __builtin_amdgcn_sched_barrier(0);
      STAGE_HALF(A, m0 + 128, Aalt + 8192, 31, 2048);
      asm volatile("s_waitcnt lgkmcnt(8)" ::: "memory");
      PHASE_SYNC_PRE()
      MFMA_QUAD(0)
      PHASE_SYNC_POST()
    }
    { LOAD_AFR(1) PHASE_SYNC_PRE() MFMA_QUAD(1) PHASE_SYNC_POST() }
    { LOAD_AFR(2) PHASE_SYNC_PRE() MFMA_QUAD(2) PHASE_SYNC_POST() }
    {
      LOAD_AFR(3)
      PHASE_SYNC_PRE()
      MFMA_QUAD(3)
      __builtin_amdgcn_s_setprio(0);
      asm volatile("s_waitcnt vmcnt(0)" ::: "memory");
      asm volatile("" ::: "memory");
      __builtin_amdgcn_s_barrier();
    }
    unsigned short* t;
    t = Acur; Acur = Aalt; Aalt = t;
    t = Bcur; Bcur = Balt; Balt = t;
  }

  // ---- tile 31: pure compute ----
  {
    const unsigned short* pA = Acur + (wr * 128 + lane15) * 64;
    const unsigned short* pB = Bcur + (wc * 64 + lane15) * 64;
    bf16x8 bfr[4][2];
#pragma unroll
    for (int n = 0; n < 4; n++)
#pragma unroll
      for (int kk = 0; kk < 2; kk++)
        bfr[n][kk] = *(const bf16x8*)(pB + n * 1024 + aks[kk]);
#pragma unroll
    for (int p = 0; p < 4; p++) {
      bf16x8 afr[2][2];
#pragma unroll
      for (int mi = 0; mi < 2; mi++)
#pragma unroll
        for (int kk = 0; kk < 2; kk++)
          afr[mi][kk] = *(const bf16x8*)(pA + (2 * p + mi) * 1024 + aks[kk]);
#pragma unroll
      for (int kk = 0; kk < 2; kk++)
#pragma unroll
        for (int mi = 0; mi < 2; mi++)
#pragma unroll
          for (int n = 0; n < 4; n++)
            acc[2 * p + mi][n] = __builtin_amdgcn_mfma_f32_16x16x32_bf16(
                afr[mi][kk], bfr[n][kk], acc[2 * p + mi][n], 0, 0, 0);
    }
  }

  // ---- fused epilogue: out[b,o,n',t] = acc + W1x + bias (fp32 store) ----
  // W1x read: Yc3[col][row..row+3] = ushort4 (8B), rows = n' consecutive.
#pragma unroll
  for (int mt = 0; mt < 8; mt++) {
    const int row = m0 + wr * 128 + mt * 16 + quad * 4;
#pragma unroll
    for (int nf = 0; nf < 4; nf++) {
      const int col = n0 + wc * 64 + nf * 16 + lane15;
      const int bo_idx = col >> 6;                    // b*32+o (uniform)
      const float bo = bm[bo_idx & 31];
      const size_t obase = (size_t)bo_idx * 65536 + (col & 63);
      ushort4 yv = *(const ushort4*)(Yc + (size_t)col * 3072 + row);
      out[obase + (size_t)(row + 0) * 64] = acc[mt][nf][0] + bf2f(yv.x) + bo;
      out[obase + (size_t)(row + 1) * 64] = acc[mt][nf][1] + bf2f(yv.y) + bo;
      out[obase + (size_t)(row + 2) * 64] = acc[mt][nf][2] + bf2f(yv.z) + bo;
      out[obase + (size_t)(row + 3) * 64] = acc[mt][nf][3] + bf2f(yv.w) + bo;
    }
  }
#undef STAGE_HALF
#undef LOAD_AFR
#undef MFMA_QUAD
#undef PHASE_SYNC_PRE
#undef PHASE_SYNC_POST
}

extern "C" void kernel_launch(void* const* d_in, const int* in_sizes, int n_in,
                              void* d_out, int out_size, void* d_ws, size_t ws_size,
                              hipStream_t stream) {
  const float* x  = (const float*)d_in[0];
  const float* AL = (const float*)d_in[1];
  const float* AS = (const float*)d_in[2];
  const float* W  = (const float*)d_in[3];
  const float* bm = (const float*)d_in[4];
  float* out = (float*)d_out;
  char* ws = (char*)d_ws;

  unsigned short* Yc    = (unsigned short*)(ws + OFF_YC);
  unsigned short* ALbf  = (unsigned short*)(ws + OFF_ALBF);
  unsigned short* ALt   = (unsigned short*)(ws + OFF_ALT);
  unsigned short* ASbf  = (unsigned short*)(ws + OFF_ASBF);
  unsigned short* ASt   = (unsigned short*)(ws + OFF_AST);
  unsigned short* AL2   = (unsigned short*)(ws + OFF_AL2);
  unsigned short* ASAL  = (unsigned short*)(ws + OFF_ASAL);
  unsigned short* AS2   = (unsigned short*)(ws + OFF_AS2);
  unsigned short* AL3   = (unsigned short*)(ws + OFF_AL3);
  unsigned short* AS2AL = (unsigned short*)(ws + OFF_AS2AL);
  unsigned short* Gm    = (unsigned short*)(ws + OFF_G);
  unsigned short* Wall  = (unsigned short*)(ws + OFF_ALBF);  // reused after stage0

  // 1) small casts + transposes (bf16 operands for precompute GEMMs)
  k_cast_bf16<<<1024, 256, 0, stream>>>(AL, ALbf, 262144);
  k_cast_bf16<<<1024, 256, 0, stream>>>(AS, ASbf, 262144);
  k_transpose_cast<<<dim3(16, 16, 1), 256, 0, stream>>>(AL, ALt, 1024, 1024);
  k_transpose_cast<<<dim3(16, 16, 1), 256, 0, stream>>>(AS, ASt, 1024, 1024);
  // 2) G pieces: {AL2, ASAL, AS2} then {AL3, AS2AL}
  k_gemm_pre<<<dim3(8, 8, 3), 256, 0, stream>>>(ws, 0);
  k_gemm_pre<<<dim3(8, 8, 2), 256, 0, stream>>>(ws, 1);
  k_assemble_G<<<4096, 256, 0, stream>>>(AL2, ASAL, AS, AL3, AS2, AS2AL, Gm);
  // 3) W -> Wall bf16 [96][32] (into retired ALbf slot)
  k_cast_wall<<<12, 256, 0, stream>>>(W, Wall);
  // 4) channel mix: x -> Yc3[j][3072] = [W1x | W2x | W3x]
  k_mix_g<<<1024, 256, 0, stream>>>(x, Wall, Yc);
  // 5) fused graph GEMM + epilogue: out = Gcat @ [W2x|W3x]^T + W1x + bias
  k_gemm_main8<<<dim3(512, 1, 1), 512, 0, stream>>>(Gm, Yc, bm, out);
}

// Round 5
// 519.134 us; speedup vs baseline: 1.3156x; 1.3156x over previous
//
#include <hip/hip_runtime.h>

// ---------------------------------------------------------------------------
// SDGL gcn_module: out = W1*x + W2*(G1 x) + W3*(G2 x) + b
//   G1 = AL^2 + AS - AS*AL ; G2 = AL^3 + AS^2 - AS2*AL   (per-slice linear op)
// KEY: channel-mix (over c) commutes with graph ops (over n):
//   W2*(G1 x) = G1*(W2 x).  Mix FIRST (K=32 MFMA, one pass over x), then one
//   fused graph GEMM (K=2048), epilogue out = V + W1x + bias.
// R5: Yc GROUP-PLANE layout Yc[G][j][8], G = og*128 + n/8 (og 0:W1x 1:W2x
//   2:W3x).  Mix writes its natural 16B granule (8 n, fixed o,t) DENSE:
//   quad = 256B contiguous, block = 32KB/og contiguous -> zero write-amp
//   (R3 2.7x, R4 3.1x from cross-block 128B-line assembly).  GEMM B-stage
//   reads the granule at Yc + (128+kt*8+c)*262144 + j*8 (full lines per
//   equal-c lane groups); swizzle relation unchanged.  Epilogue reads W1x
//   ushort4 from plane G=row>>3.  Mix uses R3 grid (2048 blocks, 62% occ).
// ---------------------------------------------------------------------------

typedef __bf16 bf16x8 __attribute__((ext_vector_type(8)));
typedef float f32x4 __attribute__((ext_vector_type(4)));
typedef unsigned int u32x4 __attribute__((ext_vector_type(4)));
typedef unsigned int u32x2 __attribute__((ext_vector_type(2)));

__device__ __forceinline__ unsigned short f2bf(float f) {
  unsigned u = __builtin_bit_cast(unsigned, f);
  u += 0x7fffu + ((u >> 16) & 1u);           // round-to-nearest-even
  return (unsigned short)(u >> 16);
}
__device__ __forceinline__ float bf2f(unsigned short h) {
  unsigned u = ((unsigned)h) << 16;
  return __builtin_bit_cast(float, u);
}

// ---------------- workspace layout (bytes) ----------------
static constexpr size_t OFF_YC    = 0;                      // 384*32768*8*2 = 192 MiB
static constexpr size_t OFF_ALBF  = 201326592;              // each small mat 2 MiB
static constexpr size_t OFF_ALT   = OFF_ALBF  + 2097152;
static constexpr size_t OFF_ASBF  = OFF_ALT   + 2097152;
static constexpr size_t OFF_AST   = OFF_ASBF  + 2097152;
static constexpr size_t OFF_AL2   = OFF_AST   + 2097152;
static constexpr size_t OFF_AL2T  = OFF_AL2   + 2097152;    // unused (layout keep)
static constexpr size_t OFF_ASAL  = OFF_AL2T  + 2097152;
static constexpr size_t OFF_AS2   = OFF_ASAL  + 2097152;
static constexpr size_t OFF_AL3   = OFF_AS2   + 2097152;
static constexpr size_t OFF_AS2AL = OFF_AL3   + 2097152;
static constexpr size_t OFF_G     = OFF_AS2AL + 2097152;    // 1024*2048*2 = 4 MiB
// Wall (96x32 bf16, 6 KiB) reuses OFF_ALBF after stage0 retires ALbf.

// ---------------- simple fp32 -> bf16 cast ----------------
__global__ __launch_bounds__(256) void k_cast_bf16(const float* __restrict__ src,
                                                   unsigned short* __restrict__ dst,
                                                   int n4) {
  int i = blockIdx.x * 256 + threadIdx.x;
  if (i < n4) {
    float4 v = *((const float4*)src + i);
    unsigned lo = (unsigned)f2bf(v.x) | ((unsigned)f2bf(v.y) << 16);
    unsigned hi = (unsigned)f2bf(v.z) | ((unsigned)f2bf(v.w) << 16);
    u32x2 pk = {lo, hi};
    *(u32x2*)(dst + (size_t)i * 4) = pk;
  }
}

// ---------------- Wall[g*32+o][c] = W[o][g*32+c] bf16 ----------------
__global__ __launch_bounds__(256) void k_cast_wall(const float* __restrict__ W,
                                                   unsigned short* __restrict__ Wall) {
  int i = blockIdx.x * 256 + threadIdx.x;   // 3072
  if (i < 3072) {
    int oo = i >> 5, c = i & 31;
    int o = oo & 31, g = oo >> 5;
    Wall[i] = f2bf(W[o * 96 + g * 32 + c]);
  }
}

// ---------------- 64x64 tiled transpose + cast (AL/AS only) ----------------
__global__ __launch_bounds__(256) void k_transpose_cast(const float* __restrict__ src,
                                                        unsigned short* __restrict__ dst,
                                                        int R, int Cc) {
  __shared__ float Xs[64][65];
  const int tid = threadIdx.x;
  const size_t slice = (size_t)blockIdx.z * (size_t)R * (size_t)Cc;
  const float* s = src + slice;
  unsigned short* d = dst + slice;
  const int r0 = blockIdx.x * 64, c0 = blockIdx.y * 64;
  const int lrow = tid >> 4, lc4 = tid & 15;
#pragma unroll
  for (int rr = 0; rr < 4; rr++) {
    int row = rr * 16 + lrow;
    float4 v = *(const float4*)(s + (size_t)(r0 + row) * Cc + c0 + lc4 * 4);
    Xs[row][lc4 * 4 + 0] = v.x;
    Xs[row][lc4 * 4 + 1] = v.y;
    Xs[row][lc4 * 4 + 2] = v.z;
    Xs[row][lc4 * 4 + 3] = v.w;
  }
  __syncthreads();
  const int wc = tid & 7;
#pragma unroll
  for (int u = 0; u < 2; u++) {
    int t = u * 32 + (tid >> 3);
    unsigned v0 = (unsigned)f2bf(Xs[wc * 8 + 0][t]) | ((unsigned)f2bf(Xs[wc * 8 + 1][t]) << 16);
    unsigned v1 = (unsigned)f2bf(Xs[wc * 8 + 2][t]) | ((unsigned)f2bf(Xs[wc * 8 + 3][t]) << 16);
    unsigned v2 = (unsigned)f2bf(Xs[wc * 8 + 4][t]) | ((unsigned)f2bf(Xs[wc * 8 + 5][t]) << 16);
    unsigned v3 = (unsigned)f2bf(Xs[wc * 8 + 6][t]) | ((unsigned)f2bf(Xs[wc * 8 + 7][t]) << 16);
    u32x4 pk = {v0, v1, v2, v3};
    *(u32x4*)(d + (size_t)(c0 + t) * R + r0 + wc * 8) = pk;
  }
}

// ---------------- core 128x128 bf16 GEMM, C = A * Bt^T (pre-GEMMs) ----------
__device__ __forceinline__ void gemm128_bt(const unsigned short* __restrict__ A,
                                           const unsigned short* __restrict__ Bt,
                                           unsigned short* __restrict__ Cp,
                                           int K, size_t ldc, int m0, int n0) {
  __shared__ unsigned short As[128 * 32];
  __shared__ unsigned short Bs[128 * 32];
  const int tid = threadIdx.x;
  const int wave = tid >> 6, lane = tid & 63;
  const int lane15 = lane & 15, quad = lane >> 4;
  const int wm = wave & 1, wn = wave >> 1;
  const int srow = lane >> 2;
  const int schunk = (lane & 3) * 8;

  const unsigned short* gA0 = A + (size_t)(m0 + wave * 16 + srow) * K + schunk;
  const unsigned short* gA1 = A + (size_t)(m0 + 64 + wave * 16 + srow) * K + schunk;
  const unsigned short* gB0 = Bt + (size_t)(n0 + wave * 16 + srow) * K + schunk;
  const unsigned short* gB1 = Bt + (size_t)(n0 + 64 + wave * 16 + srow) * K + schunk;
  unsigned short* lA0 = As + (wave * 16) * 32;
  unsigned short* lA1 = As + (64 + wave * 16) * 32;
  unsigned short* lB0 = Bs + (wave * 16) * 32;
  unsigned short* lB1 = Bs + (64 + wave * 16) * 32;

  f32x4 acc[4][4];
#pragma unroll
  for (int i = 0; i < 4; i++)
#pragma unroll
    for (int j = 0; j < 4; j++) acc[i][j] = (f32x4){0.f, 0.f, 0.f, 0.f};

  const unsigned short* pa = As + (wm * 64 + lane15) * 32 + quad * 8;
  const unsigned short* pb = Bs + (wn * 64 + lane15) * 32 + quad * 8;

  for (int kb = 0; kb < K; kb += 32) {
    __syncthreads();
    __builtin_amdgcn_global_load_lds(
        (const __attribute__((address_space(1))) unsigned int*)(gA0 + kb),
        (__attribute__((address_space(3))) unsigned int*)lA0, 16, 0, 0);
    __builtin_amdgcn_global_load_lds(
        (const __attribute__((address_space(1))) unsigned int*)(gA1 + kb),
        (__attribute__((address_space(3))) unsigned int*)lA1, 16, 0, 0);
    __builtin_amdgcn_global_load_lds(
        (const __attribute__((address_space(1))) unsigned int*)(gB0 + kb),
        (__attribute__((address_space(3))) unsigned int*)lB0, 16, 0, 0);
    __builtin_amdgcn_global_load_lds(
        (const __attribute__((address_space(1))) unsigned int*)(gB1 + kb),
        (__attribute__((address_space(3))) unsigned int*)lB1, 16, 0, 0);
    __syncthreads();

    bf16x8 av[4], bv[4];
#pragma unroll
    for (int mt = 0; mt < 4; mt++) av[mt] = *(const bf16x8*)(pa + mt * 16 * 32);
#pragma unroll
    for (int nt = 0; nt < 4; nt++) bv[nt] = *(const bf16x8*)(pb + nt * 16 * 32);
#pragma unroll
    for (int mt = 0; mt < 4; mt++)
#pragma unroll
      for (int nt = 0; nt < 4; nt++)
        acc[mt][nt] = __builtin_amdgcn_mfma_f32_16x16x32_bf16(av[mt], bv[nt], acc[mt][nt], 0, 0, 0);
  }

#pragma unroll
  for (int mt = 0; mt < 4; mt++) {
#pragma unroll
    for (int nt = 0; nt < 4; nt++) {
      const int col = n0 + wn * 64 + nt * 16 + lane15;
#pragma unroll
      for (int r = 0; r < 4; r++) {
        const int row = m0 + wm * 64 + mt * 16 + quad * 4 + r;
        Cp[(size_t)row * ldc + col] = f2bf(acc[mt][nt][r]);
      }
    }
  }
}

// ---------------- G-precompute GEMMs (batched by z; 5 total) ----------------
__global__ __launch_bounds__(256) void k_gemm_pre(char* ws, int stage) {
  const unsigned short* A;
  const unsigned short* Bt;
  unsigned short* Cp;
  const int z = blockIdx.z;
  unsigned short* ALbf = (unsigned short*)(ws + OFF_ALBF);
  unsigned short* ALt  = (unsigned short*)(ws + OFF_ALT);
  unsigned short* ASbf = (unsigned short*)(ws + OFF_ASBF);
  unsigned short* ASt  = (unsigned short*)(ws + OFF_AST);
  unsigned short* AL2  = (unsigned short*)(ws + OFF_AL2);
  unsigned short* ASAL = (unsigned short*)(ws + OFF_ASAL);
  unsigned short* AS2  = (unsigned short*)(ws + OFF_AS2);
  unsigned short* AL3  = (unsigned short*)(ws + OFF_AL3);
  unsigned short* AS2AL= (unsigned short*)(ws + OFF_AS2AL);
  if (stage == 0) {
    if (z == 0)      { A = ALbf; Bt = ALt;  Cp = AL2;  }   // AL^2
    else if (z == 1) { A = ASbf; Bt = ALt;  Cp = ASAL; }   // AS*AL
    else             { A = ASbf; Bt = ASt;  Cp = AS2;  }   // AS^2
  } else {
    if (z == 0)      { A = AL2;  Bt = ALt;  Cp = AL3;  }   // AL^2*AL = AL^3
    else             { A = AS2;  Bt = ALt;  Cp = AS2AL;}   // AS^2*AL
  }
  gemm128_bt(A, Bt, Cp, 1024, 1024, blockIdx.y * 128, blockIdx.x * 128);
}

// ---------------- assemble Gcat[1024][2048] = [G1 | G2] bf16 ----------------
__global__ __launch_bounds__(256) void k_assemble_G(const unsigned short* __restrict__ AL2,
                                                    const unsigned short* __restrict__ ASAL,
                                                    const float* __restrict__ ASf,
                                                    const unsigned short* __restrict__ AL3,
                                                    const unsigned short* __restrict__ AS2,
                                                    const unsigned short* __restrict__ AS2AL,
                                                    unsigned short* __restrict__ G) {
  int i = blockIdx.x * 256 + threadIdx.x;           // over 1024*1024
  int r = i >> 10, c = i & 1023;
  float g1 = bf2f(AL2[i]) + ASf[i] - bf2f(ASAL[i]);
  float g2 = bf2f(AL3[i]) + bf2f(AS2[i]) - bf2f(AS2AL[i]);
  G[(size_t)r * 2048 + c]        = f2bf(g1);
  G[(size_t)r * 2048 + 1024 + c] = f2bf(g2);
}

// ---------------- k_mix_g: channel mix via MFMA (K=32) ----------------
// R5: output Yc[G][j][8] planes, G = og*128 + n8 (j = (b,o,t)).  grid 2048 =
// 16 b x 128 n8 (8 n each), 256 thr / 4 waves (t-quads), XCD-chunked decode.
// Store: per (og, o-row r): 16B granule (8 n) at j = (b*32+o+r)*64+t; quad's
// 16 lanes (consecutive t) -> 256B contiguous; block covers 2048 consecutive
// j -> 32KB dense span per og.  Zero write amplification.
// B-frags: x[b, c=quad*8+e, n, t] fp32 (64B segments), A-frags: Wall rows.
__global__ __launch_bounds__(256, 8) void k_mix_g(const float* __restrict__ x,
                                                  const unsigned short* __restrict__ Wall,
                                                  unsigned short* __restrict__ Yc) {
  const int tid = threadIdx.x;
  // inverse-XCD chunking: XCD k owns sid in [k*256,(k+1)*256)
  const int sid = (blockIdx.x & 7) * 256 + (blockIdx.x >> 3);
  const int b   = sid >> 7;
  const int n8g = sid & 127;                 // group of 8 n's
  const int nbase = n8g * 8;
  const int wave = tid >> 6, lane = tid & 63;
  const int lane15 = lane & 15, quad = lane >> 4;
  const int t = wave * 16 + lane15;

  // A-frags: Wall[96][32] bf16, row = ot*16+lane15, k-chunk = quad*8
  bf16x8 afr[6];
#pragma unroll
  for (int ot = 0; ot < 6; ot++)
    afr[ot] = *(const bf16x8*)(Wall + (ot * 16 + lane15) * 32 + quad * 8);

  const float* xb = x + (size_t)b * 2097152 + (size_t)(quad * 8) * 65536 + t;

  bf16x8 bfr[8];
#pragma unroll
  for (int nl = 0; nl < 8; nl++) {
    const float* xp = xb + (size_t)(nbase + nl) * 64;
    unsigned u[4];
#pragma unroll
    for (int e = 0; e < 4; e++) {
      float a  = xp[(size_t)(2 * e) * 65536];
      float c2 = xp[(size_t)(2 * e + 1) * 65536];
      u[e] = (unsigned)f2bf(a) | ((unsigned)f2bf(c2) << 16);
    }
    u32x4 pk = {u[0], u[1], u[2], u[3]};
    bfr[nl] = __builtin_bit_cast(bf16x8, pk);
  }

#pragma unroll
  for (int ot = 0; ot < 6; ot++) {
    f32x4 acc[8];
    const f32x4 z = (f32x4){0.f, 0.f, 0.f, 0.f};
#pragma unroll
    for (int nl = 0; nl < 8; nl++)
      acc[nl] = __builtin_amdgcn_mfma_f32_16x16x32_bf16(afr[ot], bfr[nl], z, 0, 0, 0);
    const int og = ot >> 1;                       // 0:W1x 1:W2x 2:W3x
    const int o  = (ot & 1) * 16 + quad * 4;      // + r
    const size_t plane = (size_t)(og * 128 + n8g) * 262144;   // 32768*8 shorts
#pragma unroll
    for (int r = 0; r < 4; r++) {
      unsigned u0 = (unsigned)f2bf(acc[0][r]) | ((unsigned)f2bf(acc[1][r]) << 16);
      unsigned u1 = (unsigned)f2bf(acc[2][r]) | ((unsigned)f2bf(acc[3][r]) << 16);
      unsigned u2 = (unsigned)f2bf(acc[4][r]) | ((unsigned)f2bf(acc[5][r]) << 16);
      unsigned u3 = (unsigned)f2bf(acc[6][r]) | ((unsigned)f2bf(acc[7][r]) << 16);
      u32x4 pk = {u0, u1, u2, u3};
      size_t j = (size_t)(b * 32 + o + r) * 64 + t;
      *(u32x4*)(Yc + plane + j * 8) = pk;
    }
  }
}

// ---------------- main GEMM: out = Gcat @ [W2x|W3x]^T + W1x + bias ----------
// M=1024, N=32768, K=2048 (32 K-tiles of BK=64). 512 blocks x 512 thr.
// B-operand from Yc planes G=128..383: lane's 16B granule at
// Yc + (128 + kt*8 + c)*262144 + j*8  (c = (tid&7)^(srow&7) — the usual
// swizzle, now applied through the plane index; LDS/read side unchanged).
// Epilogue reads W1x ushort4 from plane G=row>>3.  8 waves (2M x 4N);
// per-wave C = 128x64. LDS 128 KiB dbuf; counted vmcnt(6); setprio.
__global__ __launch_bounds__(512) void k_gemm_main8(const unsigned short* __restrict__ A,
                                                    const unsigned short* __restrict__ Yc,
                                                    const float* __restrict__ bm,
                                                    float* __restrict__ out) {
  __shared__ unsigned short lds[65536];   // 128 KiB
  const int tid = threadIdx.x;
  const int wave = tid >> 6, lane = tid & 63;
  const int lane15 = lane & 15, quad = lane >> 4;
  const int wr = wave >> 2, wc = wave & 3;          // 2M x 4N

  // XCD-aware bijective swizzle: nwg=512, 8 XCDs, cpx=64.
  const int bid = blockIdx.x;
  const int swz = (bid & 7) * 64 + (bid >> 3);
  const int nx = swz >> 2, my = swz & 3;            // 128 N-tiles x 4 M-tiles
  const int m0 = my * 256, n0 = nx * 256;

  const int srow = tid >> 3;                          // 0..63
  const int cB   = (tid & 7) ^ (srow & 7);            // swizzled k-chunk
  const int skc  = cB << 3;                           // shorts (A path)
  const int ldst0 = (tid & ~63) << 3;                 // shorts, wave-uniform

#define STAGE_A(rowbase, ldsptr, ktile)                                                 \
  do {                                                                                  \
    const unsigned short* _g =                                                          \
        A + (size_t)((rowbase) + srow) * 2048 + (size_t)((ktile) * 64 + skc);           \
    __builtin_amdgcn_global_load_lds(                                                   \
        (const __attribute__((address_space(1))) unsigned int*)_g,                      \
        (__attribute__((address_space(3))) unsigned int*)((ldsptr) + ldst0), 16, 0, 0); \
    __builtin_amdgcn_global_load_lds(                                                   \
        (const __attribute__((address_space(1))) unsigned int*)(_g + 131072),           \
        (__attribute__((address_space(3))) unsigned int*)((ldsptr) + 4096 + ldst0),     \
        16, 0, 0);                                                                      \
  } while (0)

#define STAGE_B(rowbase, ldsptr, ktile)                                                 \
  do {                                                                                  \
    const unsigned short* _g = Yc + (size_t)(128 + (ktile) * 8 + cB) * 262144 +         \
                               (size_t)((rowbase) + srow) * 8;                          \
    __builtin_amdgcn_global_load_lds(                                                   \
        (const __attribute__((address_space(1))) unsigned int*)_g,                      \
        (__attribute__((address_space(3))) unsigned int*)((ldsptr) + ldst0), 16, 0, 0); \
    __builtin_amdgcn_global_load_lds(                                                   \
        (const __attribute__((address_space(1))) unsigned int*)(_g + 512),              \
        (__attribute__((address_space(3))) unsigned int*)((ldsptr) + 4096 + ldst0),     \
        16, 0, 0);                                                                      \
  } while (0)

#define LOAD_AFR(p)                                                                     \
  bf16x8 afr[2][2];                                                                     \
  _Pragma("unroll") for (int mi = 0; mi < 2; mi++)                                      \
      _Pragma("unroll") for (int kk = 0; kk < 2; kk++)                                  \
          afr[mi][kk] = *(const bf16x8*)(pA + (2 * (p) + mi) * 1024 + aks[kk]);

#define MFMA_QUAD(p)                                                                    \
  _Pragma("unroll") for (int kk = 0; kk < 2; kk++)                                      \
      _Pragma("unroll") for (int mi = 0; mi < 2; mi++)                                  \
          _Pragma("unroll") for (int n = 0; n < 4; n++)                                 \
              acc[2 * (p) + mi][n] = __builtin_amdgcn_mfma_f32_16x16x32_bf16(           \
                  afr[mi][kk], bfr[n][kk], acc[2 * (p) + mi][n], 0, 0, 0);

#define PHASE_SYNC_PRE()                              \
  asm volatile("" ::: "memory");                      \
  __builtin_amdgcn_s_barrier();                       \
  asm volatile("s_waitcnt lgkmcnt(0)" ::: "memory");  \
  __builtin_amdgcn_sched_barrier(0);                  \
  __builtin_amdgcn_s_setprio(1);

#define PHASE_SYNC_POST()                             \
  __builtin_amdgcn_s_setprio(0);                      \
  asm volatile("" ::: "memory");                      \
  __builtin_amdgcn_s_barrier();

  unsigned short* Acur = lds;
  unsigned short* Bcur = lds + 16384;
  unsigned short* Aalt = lds + 32768;
  unsigned short* Balt = lds + 49152;

  f32x4 acc[8][4];
#pragma unroll
  for (int i = 0; i < 8; i++)
#pragma unroll
    for (int j = 0; j < 4; j++) acc[i][j] = (f32x4){0.f, 0.f, 0.f, 0.f};

  const int swz8 = (lane15 & 7) << 3;
  int aks[2];
  aks[0] = (quad << 3) ^ swz8;
  aks[1] = (32 | (quad << 3)) ^ swz8;

  // ---- prologue: tile0 fully + tile1 {B0,B1,A0}; vmcnt(6) => tile0 landed ----
  STAGE_B(n0,       Bcur,        0);
  STAGE_B(n0 + 128, Bcur + 8192, 0);
  STAGE_A(m0,       Acur,        0);
  STAGE_A(m0 + 128, Acur + 8192, 0);
  STAGE_B(n0,       Balt,        1);
  STAGE_B(n0 + 128, Balt + 8192, 1);
  STAGE_A(m0,       Aalt,        1);
  asm volatile("s_waitcnt vmcnt(6)" ::: "memory");
  __builtin_amdgcn_s_barrier();

  // ---- main loop: tiles 0..29 with full staging ----
  for (int u = 0; u < 30; ++u) {
    const unsigned short* pA = Acur + (wr * 128 + lane15) * 64;
    const unsigned short* pB = Bcur + (wc * 64 + lane15) * 64;
    bf16x8 bfr[4][2];
    {   // phase 0: B frags (8) + A quad 0; stage A1(u+1) -> alt
#pragma unroll
      for (int n = 0; n < 4; n++)
#pragma unroll
        for (int kk = 0; kk < 2; kk++)
          bfr[n][kk] = *(const bf16x8*)(pB + n * 1024 + aks[kk]);
      LOAD_AFR(0)
      __builtin_amdgcn_sched_barrier(0);
      STAGE_A(m0 + 128, Aalt + 8192, u + 1);
      asm volatile("s_waitcnt lgkmcnt(8)" ::: "memory");
      PHASE_SYNC_PRE()
      MFMA_QUAD(0)
      PHASE_SYNC_POST()
    }
    {   // phase 1: stage B0(u+2) -> cur (B(u) reads retired at p0)
      LOAD_AFR(1)
      __builtin_amdgcn_sched_barrier(0);
      STAGE_B(n0, Bcur, u + 2);
      PHASE_SYNC_PRE()
      MFMA_QUAD(1)
      PHASE_SYNC_POST()
    }
    {   // phase 2: stage B1(u+2) -> cur
      LOAD_AFR(2)
      __builtin_amdgcn_sched_barrier(0);
      STAGE_B(n0 + 128, Bcur + 8192, u + 2);
      PHASE_SYNC_PRE()
      MFMA_QUAD(2)
      PHASE_SYNC_POST()
    }
    {   // phase 3: stage A0(u+2) -> cur ; counted vmcnt(6) => tile u+1 complete
      LOAD_AFR(3)
      __builtin_amdgcn_sched_barrier(0);
      STAGE_A(m0, Acur, u + 2);
      PHASE_SYNC_PRE()
      MFMA_QUAD(3)
      __builtin_amdgcn_s_setprio(0);
      asm volatile("s_waitcnt vmcnt(6)" ::: "memory");
      asm volatile("" ::: "memory");
      __builtin_amdgcn_s_barrier();
    }
    unsigned short* t;
    t = Acur; Acur = Aalt; Aalt = t;
    t = Bcur; Bcur = Balt; Balt = t;
  }

  // ---- tile 30: last stage (A1 of tile 31), then full drain ----
  {
    const unsigned short* pA = Acur + (wr * 128 + lane15) * 64;
    const unsigned short* pB = Bcur + (wc * 64 + lane15) * 64;
    bf16x8 bfr[4][2];
    {
#pragma unroll
      for (int n = 0; n < 4; n++)
#pragma unroll
        for (int kk = 0; kk < 2; kk++)
          bfr[n][kk] = *(const bf16x8*)(pB + n * 1024 + aks[kk]);
      LOAD_AFR(0)
      __builtin_amdgcn_sched_barrier(0);
      STAGE_A(m0 + 128, Aalt + 8192, 31);
      asm volatile("s_waitcnt lgkmcnt(8)" ::: "memory");
      PHASE_SYNC_PRE()
      MFMA_QUAD(0)
      PHASE_SYNC_POST()
    }
    { LOAD_AFR(1) PHASE_SYNC_PRE() MFMA_QUAD(1) PHASE_SYNC_POST() }
    { LOAD_AFR(2) PHASE_SYNC_PRE() MFMA_QUAD(2) PHASE_SYNC_POST() }
    {
      LOAD_AFR(3)
      PHASE_SYNC_PRE()
      MFMA_QUAD(3)
      __builtin_amdgcn_s_setprio(0);
      asm volatile("s_waitcnt vmcnt(0)" ::: "memory");
      asm volatile("" ::: "memory");
      __builtin_amdgcn_s_barrier();
    }
    unsigned short* t;
    t = Acur; Acur = Aalt; Aalt = t;
    t = Bcur; Bcur = Balt; Balt = t;
  }

  // ---- tile 31: pure compute ----
  {
    const unsigned short* pA = Acur + (wr * 128 + lane15) * 64;
    const unsigned short* pB = Bcur + (wc * 64 + lane15) * 64;
    bf16x8 bfr[4][2];
#pragma unroll
    for (int n = 0; n < 4; n++)
#pragma unroll
      for (int kk = 0; kk < 2; kk++)
        bfr[n][kk] = *(const bf16x8*)(pB + n * 1024 + aks[kk]);
#pragma unroll
    for (int p = 0; p < 4; p++) {
      bf16x8 afr[2][2];
#pragma unroll
      for (int mi = 0; mi < 2; mi++)
#pragma unroll
        for (int kk = 0; kk < 2; kk++)
          afr[mi][kk] = *(const bf16x8*)(pA + (2 * p + mi) * 1024 + aks[kk]);
#pragma unroll
      for (int kk = 0; kk < 2; kk++)
#pragma unroll
        for (int mi = 0; mi < 2; mi++)
#pragma unroll
          for (int n = 0; n < 4; n++)
            acc[2 * p + mi][n] = __builtin_amdgcn_mfma_f32_16x16x32_bf16(
                afr[mi][kk], bfr[n][kk], acc[2 * p + mi][n], 0, 0, 0);
    }
  }

  // ---- fused epilogue: out[b,o,n',t] = acc + W1x + bias (fp32 store) ----
  // W1x: ushort4 from plane G=row>>3, offset col*8 + (row&7).
#pragma unroll
  for (int mt = 0; mt < 8; mt++) {
    const int row = m0 + wr * 128 + mt * 16 + quad * 4;
#pragma unroll
    for (int nf = 0; nf < 4; nf++) {
      const int col = n0 + wc * 64 + nf * 16 + lane15;
      const int bo_idx = col >> 6;                    // b*32+o (uniform)
      const float bo = bm[bo_idx & 31];
      const size_t obase = (size_t)bo_idx * 65536 + (col & 63);
      ushort4 yv = *(const ushort4*)(Yc + (size_t)(row >> 3) * 262144 +
                                     (size_t)col * 8 + (row & 7));
      out[obase + (size_t)(row + 0) * 64] = acc[mt][nf][0] + bf2f(yv.x) + bo;
      out[obase + (size_t)(row + 1) * 64] = acc[mt][nf][1] + bf2f(yv.y) + bo;
      out[obase + (size_t)(row + 2) * 64] = acc[mt][nf][2] + bf2f(yv.z) + bo;
      out[obase + (size_t)(row + 3) * 64] = acc[mt][nf][3] + bf2f(yv.w) + bo;
    }
  }
#undef STAGE_A
#undef STAGE_B
#undef LOAD_AFR
#undef MFMA_QUAD
#undef PHASE_SYNC_PRE
#undef PHASE_SYNC_POST
}

extern "C" void kernel_launch(void* const* d_in, const int* in_sizes, int n_in,
                              void* d_out, int out_size, void* d_ws, size_t ws_size,
                              hipStream_t stream) {
  const float* x  = (const float*)d_in[0];
  const float* AL = (const float*)d_in[1];
  const float* AS = (const float*)d_in[2];
  const float* W  = (const float*)d_in[3];
  const float* bm = (const float*)d_in[4];
  float* out = (float*)d_out;
  char* ws = (char*)d_ws;

  unsigned short* Yc    = (unsigned short*)(ws + OFF_YC);
  unsigned short* ALbf  = (unsigned short*)(ws + OFF_ALBF);
  unsigned short* ALt   = (unsigned short*)(ws + OFF_ALT);
  unsigned short* ASbf  = (unsigned short*)(ws + OFF_ASBF);
  unsigned short* ASt   = (unsigned short*)(ws + OFF_AST);
  unsigned short* AL2   = (unsigned short*)(ws + OFF_AL2);
  unsigned short* ASAL  = (unsigned short*)(ws + OFF_ASAL);
  unsigned short* AS2   = (unsigned short*)(ws + OFF_AS2);
  unsigned short* AL3   = (unsigned short*)(ws + OFF_AL3);
  unsigned short* AS2AL = (unsigned short*)(ws + OFF_AS2AL);
  unsigned short* Gm    = (unsigned short*)(ws + OFF_G);
  unsigned short* Wall  = (unsigned short*)(ws + OFF_ALBF);  // reused after stage0

  // 1) small casts + transposes (bf16 operands for precompute GEMMs)
  k_cast_bf16<<<1024, 256, 0, stream>>>(AL, ALbf, 262144);
  k_cast_bf16<<<1024, 256, 0, stream>>>(AS, ASbf, 262144);
  k_transpose_cast<<<dim3(16, 16, 1), 256, 0, stream>>>(AL, ALt, 1024, 1024);
  k_transpose_cast<<<dim3(16, 16, 1), 256, 0, stream>>>(AS, ASt, 1024, 1024);
  // 2) G pieces: {AL2, ASAL, AS2} then {AL3, AS2AL}
  k_gemm_pre<<<dim3(8, 8, 3), 256, 0, stream>>>(ws, 0);
  k_gemm_pre<<<dim3(8, 8, 2), 256, 0, stream>>>(ws, 1);
  k_assemble_G<<<4096, 256, 0, stream>>>(AL2, ASAL, AS, AL3, AS2, AS2AL, Gm);
  // 3) W -> Wall bf16 [96][32] (into retired ALbf slot)
  k_cast_wall<<<12, 256, 0, stream>>>(W, Wall);
  // 4) channel mix: x -> Yc planes [W1x | W2x | W3x]
  k_mix_g<<<2048, 256, 0, stream>>>(x, Wall, Yc);
  // 5) fused graph GEMM + epilogue: out = Gcat @ [W2x|W3x]^T + W1x + bias
  k_gemm_main8<<<dim3(512, 1, 1), 512, 0, stream>>>(Gm, Yc, bm, out);
}

// Round 7
// 517.975 us; speedup vs baseline: 1.3185x; 1.0022x over previous
//
#include <hip/hip_runtime.h>

// ---------------------------------------------------------------------------
// SDGL gcn_module: out = W1*x + W2*(G1 x) + W3*(G2 x) + b
//   G1 = AL^2 + AS - AS*AL ; G2 = AL^3 + AS^2 - AS2*AL   (per-slice linear op)
// KEY: channel-mix commutes with graph ops: W2*(G1 x) = G1*(W2 x).
// Pipeline: prep(AL,AS: bf16 natural+transposed, 1 pass) -> 5 pre-GEMMs ->
//   assemble Gcat[1024][2048] (+W cast) -> k_mix_g (x -> Yc planes
//   [W1x|W2x|W3x], group-plane layout, zero write-amp) -> fused graph GEMM
//   out = Gcat @ [W2x|W3x]^T + W1x + bias  (M=1024,N=32768,K=2048).
// R6/R7 GEMM loop: ONE barrier per phase + register-load software pipelining
//   (afr ping-pong): phase p issues phase p+1's ds_reads after its MFMA.
//   R7 hardening: every phase waits lgkmcnt(0) BEFORE its barrier, so when
//   any wave passes a barrier ALL waves' issued LDS reads are complete —
//   stages issued post-barrier are sequenced-safe (was latency-argument).
//   Tile boundary publish = counted vmcnt(4) at P3 then the P0 barrier.
// ---------------------------------------------------------------------------

typedef __bf16 bf16x8 __attribute__((ext_vector_type(8)));
typedef float f32x4 __attribute__((ext_vector_type(4)));
typedef unsigned int u32x4 __attribute__((ext_vector_type(4)));
typedef unsigned int u32x2 __attribute__((ext_vector_type(2)));

__device__ __forceinline__ unsigned short f2bf(float f) {
  unsigned u = __builtin_bit_cast(unsigned, f);
  u += 0x7fffu + ((u >> 16) & 1u);           // round-to-nearest-even
  return (unsigned short)(u >> 16);
}
__device__ __forceinline__ float bf2f(unsigned short h) {
  unsigned u = ((unsigned)h) << 16;
  return __builtin_bit_cast(float, u);
}

// ---------------- workspace layout (bytes) ----------------
static constexpr size_t OFF_YC    = 0;                      // 384*32768*8*2 = 192 MiB
static constexpr size_t OFF_ALBF  = 201326592;              // each small mat 2 MiB
static constexpr size_t OFF_ALT   = OFF_ALBF  + 2097152;
static constexpr size_t OFF_ASBF  = OFF_ALT   + 2097152;
static constexpr size_t OFF_AST   = OFF_ASBF  + 2097152;
static constexpr size_t OFF_AL2   = OFF_AST   + 2097152;
static constexpr size_t OFF_AL2T  = OFF_AL2   + 2097152;    // unused (layout keep)
static constexpr size_t OFF_ASAL  = OFF_AL2T  + 2097152;
static constexpr size_t OFF_AS2   = OFF_ASAL  + 2097152;
static constexpr size_t OFF_AL3   = OFF_AS2   + 2097152;
static constexpr size_t OFF_AS2AL = OFF_AL3   + 2097152;
static constexpr size_t OFF_G     = OFF_AS2AL + 2097152;    // 1024*2048*2 = 4 MiB
// Wall (96x32 bf16, 6 KiB) reuses OFF_ALBF after pre-GEMM stage0 retires ALbf.

// ---------------- k_prep: fp32 [1024][1024] -> bf16 natural + transposed ----
__global__ __launch_bounds__(256) void k_prep(const float* __restrict__ src,
                                              unsigned short* __restrict__ dstN,
                                              unsigned short* __restrict__ dstT) {
  __shared__ float Xs[64][65];
  const int tid = threadIdx.x;
  const int r0 = blockIdx.x * 64, c0 = blockIdx.y * 64;
  const int lrow = tid >> 4, lc4 = tid & 15;
#pragma unroll
  for (int rr = 0; rr < 4; rr++) {
    int row = rr * 16 + lrow;
    float4 v = *(const float4*)(src + (size_t)(r0 + row) * 1024 + c0 + lc4 * 4);
    Xs[row][lc4 * 4 + 0] = v.x;
    Xs[row][lc4 * 4 + 1] = v.y;
    Xs[row][lc4 * 4 + 2] = v.z;
    Xs[row][lc4 * 4 + 3] = v.w;
    unsigned lo = (unsigned)f2bf(v.x) | ((unsigned)f2bf(v.y) << 16);
    unsigned hi = (unsigned)f2bf(v.z) | ((unsigned)f2bf(v.w) << 16);
    u32x2 pk = {lo, hi};
    *(u32x2*)(dstN + (size_t)(r0 + row) * 1024 + c0 + lc4 * 4) = pk;
  }
  __syncthreads();
  const int wc = tid & 7;
#pragma unroll
  for (int u = 0; u < 2; u++) {
    int t = u * 32 + (tid >> 3);
    unsigned v0 = (unsigned)f2bf(Xs[wc * 8 + 0][t]) | ((unsigned)f2bf(Xs[wc * 8 + 1][t]) << 16);
    unsigned v1 = (unsigned)f2bf(Xs[wc * 8 + 2][t]) | ((unsigned)f2bf(Xs[wc * 8 + 3][t]) << 16);
    unsigned v2 = (unsigned)f2bf(Xs[wc * 8 + 4][t]) | ((unsigned)f2bf(Xs[wc * 8 + 5][t]) << 16);
    unsigned v3 = (unsigned)f2bf(Xs[wc * 8 + 6][t]) | ((unsigned)f2bf(Xs[wc * 8 + 7][t]) << 16);
    u32x4 pk = {v0, v1, v2, v3};
    *(u32x4*)(dstT + (size_t)(c0 + t) * 1024 + r0 + wc * 8) = pk;
  }
}

// ---------------- core 128x128 bf16 GEMM, C = A * Bt^T (pre-GEMMs) ----------
__device__ __forceinline__ void gemm128_bt(const unsigned short* __restrict__ A,
                                           const unsigned short* __restrict__ Bt,
                                           unsigned short* __restrict__ Cp,
                                           int K, size_t ldc, int m0, int n0) {
  __shared__ unsigned short As[128 * 32];
  __shared__ unsigned short Bs[128 * 32];
  const int tid = threadIdx.x;
  const int wave = tid >> 6, lane = tid & 63;
  const int lane15 = lane & 15, quad = lane >> 4;
  const int wm = wave & 1, wn = wave >> 1;
  const int srow = lane >> 2;
  const int schunk = (lane & 3) * 8;

  const unsigned short* gA0 = A + (size_t)(m0 + wave * 16 + srow) * K + schunk;
  const unsigned short* gA1 = A + (size_t)(m0 + 64 + wave * 16 + srow) * K + schunk;
  const unsigned short* gB0 = Bt + (size_t)(n0 + wave * 16 + srow) * K + schunk;
  const unsigned short* gB1 = Bt + (size_t)(n0 + 64 + wave * 16 + srow) * K + schunk;
  unsigned short* lA0 = As + (wave * 16) * 32;
  unsigned short* lA1 = As + (64 + wave * 16) * 32;
  unsigned short* lB0 = Bs + (wave * 16) * 32;
  unsigned short* lB1 = Bs + (64 + wave * 16) * 32;

  f32x4 acc[4][4];
#pragma unroll
  for (int i = 0; i < 4; i++)
#pragma unroll
    for (int j = 0; j < 4; j++) acc[i][j] = (f32x4){0.f, 0.f, 0.f, 0.f};

  const unsigned short* pa = As + (wm * 64 + lane15) * 32 + quad * 8;
  const unsigned short* pb = Bs + (wn * 64 + lane15) * 32 + quad * 8;

  for (int kb = 0; kb < K; kb += 32) {
    __syncthreads();
    __builtin_amdgcn_global_load_lds(
        (const __attribute__((address_space(1))) unsigned int*)(gA0 + kb),
        (__attribute__((address_space(3))) unsigned int*)lA0, 16, 0, 0);
    __builtin_amdgcn_global_load_lds(
        (const __attribute__((address_space(1))) unsigned int*)(gA1 + kb),
        (__attribute__((address_space(3))) unsigned int*)lA1, 16, 0, 0);
    __builtin_amdgcn_global_load_lds(
        (const __attribute__((address_space(1))) unsigned int*)(gB0 + kb),
        (__attribute__((address_space(3))) unsigned int*)lB0, 16, 0, 0);
    __builtin_amdgcn_global_load_lds(
        (const __attribute__((address_space(1))) unsigned int*)(gB1 + kb),
        (__attribute__((address_space(3))) unsigned int*)lB1, 16, 0, 0);
    __syncthreads();

    bf16x8 av[4], bv[4];
#pragma unroll
    for (int mt = 0; mt < 4; mt++) av[mt] = *(const bf16x8*)(pa + mt * 16 * 32);
#pragma unroll
    for (int nt = 0; nt < 4; nt++) bv[nt] = *(const bf16x8*)(pb + nt * 16 * 32);
#pragma unroll
    for (int mt = 0; mt < 4; mt++)
#pragma unroll
      for (int nt = 0; nt < 4; nt++)
        acc[mt][nt] = __builtin_amdgcn_mfma_f32_16x16x32_bf16(av[mt], bv[nt], acc[mt][nt], 0, 0, 0);
  }

#pragma unroll
  for (int mt = 0; mt < 4; mt++) {
#pragma unroll
    for (int nt = 0; nt < 4; nt++) {
      const int col = n0 + wn * 64 + nt * 16 + lane15;
#pragma unroll
      for (int r = 0; r < 4; r++) {
        const int row = m0 + wm * 64 + mt * 16 + quad * 4 + r;
        Cp[(size_t)row * ldc + col] = f2bf(acc[mt][nt][r]);
      }
    }
  }
}

// ---------------- G-precompute GEMMs (batched by z; 5 total) ----------------
__global__ __launch_bounds__(256) void k_gemm_pre(char* ws, int stage) {
  const unsigned short* A;
  const unsigned short* Bt;
  unsigned short* Cp;
  const int z = blockIdx.z;
  unsigned short* ALbf = (unsigned short*)(ws + OFF_ALBF);
  unsigned short* ALt  = (unsigned short*)(ws + OFF_ALT);
  unsigned short* ASbf = (unsigned short*)(ws + OFF_ASBF);
  unsigned short* ASt  = (unsigned short*)(ws + OFF_AST);
  unsigned short* AL2  = (unsigned short*)(ws + OFF_AL2);
  unsigned short* ASAL = (unsigned short*)(ws + OFF_ASAL);
  unsigned short* AS2  = (unsigned short*)(ws + OFF_AS2);
  unsigned short* AL3  = (unsigned short*)(ws + OFF_AL3);
  unsigned short* AS2AL= (unsigned short*)(ws + OFF_AS2AL);
  if (stage == 0) {
    if (z == 0)      { A = ALbf; Bt = ALt;  Cp = AL2;  }   // AL^2
    else if (z == 1) { A = ASbf; Bt = ALt;  Cp = ASAL; }   // AS*AL
    else             { A = ASbf; Bt = ASt;  Cp = AS2;  }   // AS^2
  } else {
    if (z == 0)      { A = AL2;  Bt = ALt;  Cp = AL3;  }   // AL^2*AL = AL^3
    else             { A = AS2;  Bt = ALt;  Cp = AS2AL;}   // AS^2*AL
  }
  gemm128_bt(A, Bt, Cp, 1024, 1024, blockIdx.y * 128, blockIdx.x * 128);
}

// ---------------- assemble Gcat[1024][2048] = [G1 | G2] bf16 (+W cast) ------
__global__ __launch_bounds__(256) void k_assemble_G(const unsigned short* __restrict__ AL2,
                                                    const unsigned short* __restrict__ ASAL,
                                                    const float* __restrict__ ASf,
                                                    const unsigned short* __restrict__ AL3,
                                                    const unsigned short* __restrict__ AS2,
                                                    const unsigned short* __restrict__ AS2AL,
                                                    const float* __restrict__ W,
                                                    unsigned short* __restrict__ Wall,
                                                    unsigned short* __restrict__ G) {
  if (blockIdx.x == 0) {   // fold W -> Wall[g*32+o][c] cast into block 0
    for (int k = threadIdx.x; k < 3072; k += 256) {
      int oo = k >> 5, c = k & 31;
      Wall[k] = f2bf(W[(oo & 31) * 96 + (oo >> 5) * 32 + c]);
    }
  }
  int i = blockIdx.x * 256 + threadIdx.x;           // over 1024*1024
  int r = i >> 10, c = i & 1023;
  float g1 = bf2f(AL2[i]) + ASf[i] - bf2f(ASAL[i]);
  float g2 = bf2f(AL3[i]) + bf2f(AS2[i]) - bf2f(AS2AL[i]);
  G[(size_t)r * 2048 + c]        = f2bf(g1);
  G[(size_t)r * 2048 + 1024 + c] = f2bf(g2);
}

// ---------------- k_mix_g: channel mix via MFMA (K=32) ----------------
// Output Yc[G][j][8] planes, G = og*128 + n8 (j = (b,o,t)).  grid 2048 =
// 16 b x 128 n8 (8 n each), 256 thr / 4 waves (t-quads), XCD-chunked decode.
// Stores: 16B granules, quad = 256B contiguous -> zero write amplification.
__global__ __launch_bounds__(256, 8) void k_mix_g(const float* __restrict__ x,
                                                  const unsigned short* __restrict__ Wall,
                                                  unsigned short* __restrict__ Yc) {
  const int tid = threadIdx.x;
  const int sid = (blockIdx.x & 7) * 256 + (blockIdx.x >> 3);
  const int b   = sid >> 7;
  const int n8g = sid & 127;
  const int nbase = n8g * 8;
  const int wave = tid >> 6, lane = tid & 63;
  const int lane15 = lane & 15, quad = lane >> 4;
  const int t = wave * 16 + lane15;

  bf16x8 afr[6];
#pragma unroll
  for (int ot = 0; ot < 6; ot++)
    afr[ot] = *(const bf16x8*)(Wall + (ot * 16 + lane15) * 32 + quad * 8);

  const float* xb = x + (size_t)b * 2097152 + (size_t)(quad * 8) * 65536 + t;

  bf16x8 bfr[8];
#pragma unroll
  for (int nl = 0; nl < 8; nl++) {
    const float* xp = xb + (size_t)(nbase + nl) * 64;
    unsigned u[4];
#pragma unroll
    for (int e = 0; e < 4; e++) {
      float a  = xp[(size_t)(2 * e) * 65536];
      float c2 = xp[(size_t)(2 * e + 1) * 65536];
      u[e] = (unsigned)f2bf(a) | ((unsigned)f2bf(c2) << 16);
    }
    u32x4 pk = {u[0], u[1], u[2], u[3]};
    bfr[nl] = __builtin_bit_cast(bf16x8, pk);
  }

#pragma unroll
  for (int ot = 0; ot < 6; ot++) {
    f32x4 acc[8];
    const f32x4 z = (f32x4){0.f, 0.f, 0.f, 0.f};
#pragma unroll
    for (int nl = 0; nl < 8; nl++)
      acc[nl] = __builtin_amdgcn_mfma_f32_16x16x32_bf16(afr[ot], bfr[nl], z, 0, 0, 0);
    const int og = ot >> 1;                       // 0:W1x 1:W2x 2:W3x
    const int o  = (ot & 1) * 16 + quad * 4;      // + r
    const size_t plane = (size_t)(og * 128 + n8g) * 262144;
#pragma unroll
    for (int r = 0; r < 4; r++) {
      unsigned u0 = (unsigned)f2bf(acc[0][r]) | ((unsigned)f2bf(acc[1][r]) << 16);
      unsigned u1 = (unsigned)f2bf(acc[2][r]) | ((unsigned)f2bf(acc[3][r]) << 16);
      unsigned u2 = (unsigned)f2bf(acc[4][r]) | ((unsigned)f2bf(acc[5][r]) << 16);
      unsigned u3 = (unsigned)f2bf(acc[6][r]) | ((unsigned)f2bf(acc[7][r]) << 16);
      u32x4 pk = {u0, u1, u2, u3};
      size_t j = (size_t)(b * 32 + o + r) * 64 + t;
      *(u32x4*)(Yc + plane + j * 8) = pk;
    }
  }
}

// ---------------- main GEMM: out = Gcat @ [W2x|W3x]^T + W1x + bias ----------
// M=1024, N=32768, K=2048 (32 K-tiles of BK=64). 512 blocks x 512 thr.
// Single-barrier pipelined phases; afr ping-pong; counted vmcnt(4);
// lgkmcnt(0) BEFORE each barrier (sequenced write-after-read safety).
__global__ __launch_bounds__(512) void k_gemm_main8(const unsigned short* __restrict__ A,
                                                    const unsigned short* __restrict__ Yc,
                                                    const float* __restrict__ bm,
                                                    float* __restrict__ out) {
  __shared__ unsigned short lds[65536];   // 128 KiB
  const int tid = threadIdx.x;
  const int wave = tid >> 6, lane = tid & 63;
  const int lane15 = lane & 15, quad = lane >> 4;
  const int wr = wave >> 2, wc = wave & 3;          // 2M x 4N

  const int bid = blockIdx.x;
  const int swz = (bid & 7) * 64 + (bid >> 3);      // XCD-bijective (512%8==0)
  const int nx = swz >> 2, my = swz & 3;            // 128 N-tiles x 4 M-tiles
  const int m0 = my * 256, n0 = nx * 256;

  const int srow = tid >> 3;                          // 0..63
  const int cB   = (tid & 7) ^ (srow & 7);            // swizzled k-chunk
  const int skc  = cB << 3;                           // shorts (A path)
  const int ldst0 = (tid & ~63) << 3;                 // shorts, wave-uniform

#define STAGE_A(rowbase, ldsptr, ktile)                                                 \
  do {                                                                                  \
    const unsigned short* _g =                                                          \
        A + (size_t)((rowbase) + srow) * 2048 + (size_t)((ktile) * 64 + skc);           \
    __builtin_amdgcn_global_load_lds(                                                   \
        (const __attribute__((address_space(1))) unsigned int*)_g,                      \
        (__attribute__((address_space(3))) unsigned int*)((ldsptr) + ldst0), 16, 0, 0); \
    __builtin_amdgcn_global_load_lds(                                                   \
        (const __attribute__((address_space(1))) unsigned int*)(_g + 131072),           \
        (__attribute__((address_space(3))) unsigned int*)((ldsptr) + 4096 + ldst0),     \
        16, 0, 0);                                                                      \
  } while (0)

#define STAGE_B(rowbase, ldsptr, ktile)                                                 \
  do {                                                                                  \
    const unsigned short* _g = Yc + (size_t)(128 + (ktile) * 8 + cB) * 262144 +         \
                               (size_t)((rowbase) + srow) * 8;                          \
    __builtin_amdgcn_global_load_lds(                                                   \
        (const __attribute__((address_space(1))) unsigned int*)_g,                      \
        (__attribute__((address_space(3))) unsigned int*)((ldsptr) + ldst0), 16, 0, 0); \
    __builtin_amdgcn_global_load_lds(                                                   \
        (const __attribute__((address_space(1))) unsigned int*)(_g + 512),              \
        (__attribute__((address_space(3))) unsigned int*)((ldsptr) + 4096 + ldst0),     \
        16, 0, 0);                                                                      \
  } while (0)

#define RD_BFR()                                                                        \
  _Pragma("unroll") for (int n = 0; n < 4; n++)                                         \
      _Pragma("unroll") for (int kk = 0; kk < 2; kk++)                                  \
          bfr[n][kk] = *(const bf16x8*)(pB + n * 1024 + aks[kk]);

#define RD_AFR(FR, mA, mB)                                                              \
  _Pragma("unroll") for (int kk = 0; kk < 2; kk++) {                                    \
    FR[0][kk] = *(const bf16x8*)(pA + (mA) * 1024 + aks[kk]);                           \
    FR[1][kk] = *(const bf16x8*)(pA + (mB) * 1024 + aks[kk]);                           \
  }

#define MFMA2(i0, FR)                                                                   \
  _Pragma("unroll") for (int kk = 0; kk < 2; kk++)                                      \
      _Pragma("unroll") for (int mi = 0; mi < 2; mi++)                                  \
          _Pragma("unroll") for (int n = 0; n < 4; n++)                                 \
              acc[(i0) + mi][n] = __builtin_amdgcn_mfma_f32_16x16x32_bf16(              \
                  FR[mi][kk], bfr[n][kk], acc[(i0) + mi][n], 0, 0, 0);

// lgkm-drain BEFORE barrier: sequenced WAR safety for post-barrier stages.
#define SAFEBAR()                                                                       \
  asm volatile("s_waitcnt lgkmcnt(0)" ::: "memory");                                    \
  __builtin_amdgcn_s_barrier();
#define LGKM0() asm volatile("s_waitcnt lgkmcnt(0)" ::: "memory");                      \
                __builtin_amdgcn_sched_barrier(0);
#define PRIO1() __builtin_amdgcn_s_setprio(1);
#define PRIO0() __builtin_amdgcn_s_setprio(0);

  unsigned short* Acur = lds;
  unsigned short* Bcur = lds + 16384;
  unsigned short* Aalt = lds + 32768;
  unsigned short* Balt = lds + 49152;

  f32x4 acc[8][4];
#pragma unroll
  for (int i = 0; i < 8; i++)
#pragma unroll
    for (int j = 0; j < 4; j++) acc[i][j] = (f32x4){0.f, 0.f, 0.f, 0.f};

  const int swz8 = (lane15 & 7) << 3;
  int aks[2];
  aks[0] = (quad << 3) ^ swz8;
  aks[1] = (32 | (quad << 3)) ^ swz8;

  bf16x8 bfr[4][2], afrP[2][2], afrQ[2][2];

  // ---- prologue: tile0 fully + tile1 {B0,B1,A0}; vmcnt(6) => tile0 landed ----
  STAGE_B(n0,       Bcur,        0);
  STAGE_B(n0 + 128, Bcur + 8192, 0);
  STAGE_A(m0,       Acur,        0);
  STAGE_A(m0 + 128, Acur + 8192, 0);
  STAGE_B(n0,       Balt,        1);
  STAGE_B(n0 + 128, Balt + 8192, 1);
  STAGE_A(m0,       Aalt,        1);
  asm volatile("s_waitcnt vmcnt(6)" ::: "memory");

  // ---- main loop: tiles 0..29, 4 single-barrier pipelined phases each ----
  for (int u = 0; u < 30; ++u) {
    const unsigned short* pA = Acur + (wr * 128 + lane15) * 64;
    const unsigned short* pB = Bcur + (wc * 64 + lane15) * 64;
    // P0: publish barrier (after prior vmcnt) -> fresh-tile reads -> MFMA m01
    SAFEBAR();
    RD_BFR();
    RD_AFR(afrP, 0, 1);
    LGKM0();
    PRIO1(); MFMA2(0, afrP); PRIO0();
    RD_AFR(afrQ, 2, 3);                      // prefetch next phase's frags
    STAGE_A(m0 + 128, Aalt + 8192, u + 1);   // A1(u+1) -> alt
    // P1
    SAFEBAR();
    __builtin_amdgcn_sched_barrier(0);
    PRIO1(); MFMA2(2, afrQ); PRIO0();
    RD_AFR(afrP, 4, 5);
    STAGE_B(n0, Bcur, u + 2);                // B0(u+2) -> cur (B reads done pre-bar)
    // P2
    SAFEBAR();
    __builtin_amdgcn_sched_barrier(0);
    PRIO1(); MFMA2(4, afrP); PRIO0();
    RD_AFR(afrQ, 6, 7);
    STAGE_B(n0 + 128, Bcur + 8192, u + 2);   // B1(u+2) -> cur
    // P3
    SAFEBAR();
    __builtin_amdgcn_sched_barrier(0);
    PRIO1(); MFMA2(6, afrQ); PRIO0();
    STAGE_A(m0, Acur, u + 2);                // A0(u+2) -> cur (A reads done pre-bar)
    asm volatile("s_waitcnt vmcnt(4)" ::: "memory");   // drains A1(u+1)+older
    unsigned short* t;
    t = Acur; Acur = Aalt; Aalt = t;
    t = Bcur; Bcur = Balt; Balt = t;
  }

  // ---- tile 30: stages only A1(31); end with full drain + publish ----
  {
    const unsigned short* pA = Acur + (wr * 128 + lane15) * 64;
    const unsigned short* pB = Bcur + (wc * 64 + lane15) * 64;
    SAFEBAR();
    RD_BFR();
    RD_AFR(afrP, 0, 1);
    LGKM0();
    PRIO1(); MFMA2(0, afrP); PRIO0();
    RD_AFR(afrQ, 2, 3);
    STAGE_A(m0 + 128, Aalt + 8192, 31);
    SAFEBAR();
    __builtin_amdgcn_sched_barrier(0);
    PRIO1(); MFMA2(2, afrQ); PRIO0();
    RD_AFR(afrP, 4, 5);
    SAFEBAR();
    __builtin_amdgcn_sched_barrier(0);
    PRIO1(); MFMA2(4, afrP); PRIO0();
    RD_AFR(afrQ, 6, 7);
    SAFEBAR();
    __builtin_amdgcn_sched_barrier(0);
    PRIO1(); MFMA2(6, afrQ); PRIO0();
    asm volatile("s_waitcnt vmcnt(0)" ::: "memory");
    SAFEBAR();
    unsigned short* t;
    t = Acur; Acur = Aalt; Aalt = t;
    t = Bcur; Bcur = Balt; Balt = t;
  }

  // ---- tile 31: pure compute ----
  {
    const unsigned short* pA = Acur + (wr * 128 + lane15) * 64;
    const unsigned short* pB = Bcur + (wc * 64 + lane15) * 64;
    RD_BFR();
#pragma unroll
    for (int p = 0; p < 4; p++) {
      bf16x8 afr[2][2];
#pragma unroll
      for (int mi = 0; mi < 2; mi++)
#pragma unroll
        for (int kk = 0; kk < 2; kk++)
          afr[mi][kk] = *(const bf16x8*)(pA + (2 * p + mi) * 1024 + aks[kk]);
#pragma unroll
      for (int kk = 0; kk < 2; kk++)
#pragma unroll
        for (int mi = 0; mi < 2; mi++)
#pragma unroll
          for (int n = 0; n < 4; n++)
            acc[2 * p + mi][n] = __builtin_amdgcn_mfma_f32_16x16x32_bf16(
                afr[mi][kk], bfr[n][kk], acc[2 * p + mi][n], 0, 0, 0);
    }
  }

  // ---- fused epilogue: out[b,o,n',t] = acc + W1x + bias (fp32 store) ----
#pragma unroll
  for (int mt = 0; mt < 8; mt++) {
    const int row = m0 + wr * 128 + mt * 16 + quad * 4;
#pragma unroll
    for (int nf = 0; nf < 4; nf++) {
      const int col = n0 + wc * 64 + nf * 16 + lane15;
      const int bo_idx = col >> 6;                    // b*32+o (uniform)
      const float bo = bm[bo_idx & 31];
      const size_t obase = (size_t)bo_idx * 65536 + (col & 63);
      ushort4 yv = *(const ushort4*)(Yc + (size_t)(row >> 3) * 262144 +
                                     (size_t)col * 8 + (row & 7));
      out[obase + (size_t)(row + 0) * 64] = acc[mt][nf][0] + bf2f(yv.x) + bo;
      out[obase + (size_t)(row + 1) * 64] = acc[mt][nf][1] + bf2f(yv.y) + bo;
      out[obase + (size_t)(row + 2) * 64] = acc[mt][nf][2] + bf2f(yv.z) + bo;
      out[obase + (size_t)(row + 3) * 64] = acc[mt][nf][3] + bf2f(yv.w) + bo;
    }
  }
#undef STAGE_A
#undef STAGE_B
#undef RD_BFR
#undef RD_AFR
#undef MFMA2
#undef SAFEBAR
#undef LGKM0
#undef PRIO1
#undef PRIO0
}

extern "C" void kernel_launch(void* const* d_in, const int* in_sizes, int n_in,
                              void* d_out, int out_size, void* d_ws, size_t ws_size,
                              hipStream_t stream) {
  const float* x  = (const float*)d_in[0];
  const float* AL = (const float*)d_in[1];
  const float* AS = (const float*)d_in[2];
  const float* W  = (const float*)d_in[3];
  const float* bm = (const float*)d_in[4];
  float* out = (float*)d_out;
  char* ws = (char*)d_ws;

  unsigned short* Yc    = (unsigned short*)(ws + OFF_YC);
  unsigned short* ALbf  = (unsigned short*)(ws + OFF_ALBF);
  unsigned short* ALt   = (unsigned short*)(ws + OFF_ALT);
  unsigned short* ASbf  = (unsigned short*)(ws + OFF_ASBF);
  unsigned short* ASt   = (unsigned short*)(ws + OFF_AST);
  unsigned short* AL2   = (unsigned short*)(ws + OFF_AL2);
  unsigned short* ASAL  = (unsigned short*)(ws + OFF_ASAL);
  unsigned short* AS2   = (unsigned short*)(ws + OFF_AS2);
  unsigned short* AL3   = (unsigned short*)(ws + OFF_AL3);
  unsigned short* AS2AL = (unsigned short*)(ws + OFF_AS2AL);
  unsigned short* Gm    = (unsigned short*)(ws + OFF_G);
  unsigned short* Wall  = (unsigned short*)(ws + OFF_ALBF);  // reused after stage0

  // 1) AL/AS -> bf16 natural + transposed (single pass each)
  k_prep<<<dim3(16, 16, 1), 256, 0, stream>>>(AL, ALbf, ALt);
  k_prep<<<dim3(16, 16, 1), 256, 0, stream>>>(AS, ASbf, ASt);
  // 2) G pieces: {AL2, ASAL, AS2} then {AL3, AS2AL}
  k_gemm_pre<<<dim3(8, 8, 3), 256, 0, stream>>>(ws, 0);
  k_gemm_pre<<<dim3(8, 8, 2), 256, 0, stream>>>(ws, 1);
  // 3) assemble Gcat (+ W -> Wall cast folded into block 0)
  k_assemble_G<<<4096, 256, 0, stream>>>(AL2, ASAL, AS, AL3, AS2, AS2AL, W, Wall, Gm);
  // 4) channel mix: x -> Yc planes [W1x | W2x | W3x]
  k_mix_g<<<2048, 256, 0, stream>>>(x, Wall, Yc);
  // 5) fused graph GEMM + epilogue: out = Gcat @ [W2x|W3x]^T + W1x + bias
  k_gemm_main8<<<dim3(512, 1, 1), 512, 0, stream>>>(Gm, Yc, bm, out);
}

// Round 8
// 511.196 us; speedup vs baseline: 1.3360x; 1.0133x over previous
//
#include <hip/hip_runtime.h>

// ---------------------------------------------------------------------------
// SDGL gcn_module: out = W1*x + W2*(G1 x) + W3*(G2 x) + b
//   G1 = AL^2 + AS - AS*AL ; G2 = AL^3 + AS^2 - AS2*AL   (per-slice linear op)
// KEY: channel-mix commutes with graph ops: W2*(G1 x) = G1*(W2 x).
// Pipeline: prep(AL,AS) -> 5 pre-GEMMs -> assemble Gcat[1024][2048] (+W cast)
//   -> k_mix_g (x -> Yc planes [W1x|W2x|W3x], zero write-amp) -> fused graph
//   GEMM out = Gcat @ [W2x|W3x]^T + W1x + bias  (M=1024,N=32768,K=2048).
// R8 GEMM loop (m201-faithful): per phase, ds_reads for THIS phase's MFMA and
//   the half-tile stage are issued BEFORE the leading barrier — the barrier
//   wait absorbs LDS latency (lgkmcnt(0) after barrier ~free).  Trailing
//   barrier after MFMA makes pre-barrier stages of later phases sequenced-
//   safe (all waves' reads complete before their MFMA).  Stage plan per tile
//   t: {A0(t+1), A1(t+1), B0(t+2), B1(t+2)}; counted vmcnt(4) once per tile.
//   R7 (reads after barrier + lgkm-wait) exposed a ~400cy serial LDS burst
//   every P0 with all waves stalled — neutral vs R5; this round moves the
//   latency under the barrier per m201's proven 62%-MfmaUtil schedule.
// ---------------------------------------------------------------------------

typedef __bf16 bf16x8 __attribute__((ext_vector_type(8)));
typedef float f32x4 __attribute__((ext_vector_type(4)));
typedef unsigned int u32x4 __attribute__((ext_vector_type(4)));
typedef unsigned int u32x2 __attribute__((ext_vector_type(2)));

__device__ __forceinline__ unsigned short f2bf(float f) {
  unsigned u = __builtin_bit_cast(unsigned, f);
  u += 0x7fffu + ((u >> 16) & 1u);           // round-to-nearest-even
  return (unsigned short)(u >> 16);
}
__device__ __forceinline__ float bf2f(unsigned short h) {
  unsigned u = ((unsigned)h) << 16;
  return __builtin_bit_cast(float, u);
}

// ---------------- workspace layout (bytes) ----------------
static constexpr size_t OFF_YC    = 0;                      // 384*32768*8*2 = 192 MiB
static constexpr size_t OFF_ALBF  = 201326592;              // each small mat 2 MiB
static constexpr size_t OFF_ALT   = OFF_ALBF  + 2097152;
static constexpr size_t OFF_ASBF  = OFF_ALT   + 2097152;
static constexpr size_t OFF_AST   = OFF_ASBF  + 2097152;
static constexpr size_t OFF_AL2   = OFF_AST   + 2097152;
static constexpr size_t OFF_AL2T  = OFF_AL2   + 2097152;    // unused (layout keep)
static constexpr size_t OFF_ASAL  = OFF_AL2T  + 2097152;
static constexpr size_t OFF_AS2   = OFF_ASAL  + 2097152;
static constexpr size_t OFF_AL3   = OFF_AS2   + 2097152;
static constexpr size_t OFF_AS2AL = OFF_AL3   + 2097152;
static constexpr size_t OFF_G     = OFF_AS2AL + 2097152;    // 1024*2048*2 = 4 MiB
// Wall (96x32 bf16, 6 KiB) reuses OFF_ALBF after pre-GEMM stage0 retires ALbf.

// ---------------- k_prep: fp32 [1024][1024] -> bf16 natural + transposed ----
// z = 0: AL, z = 1: AS (merged launch).
__global__ __launch_bounds__(256) void k_prep(const float* __restrict__ AL,
                                              const float* __restrict__ AS,
                                              unsigned short* __restrict__ ALn,
                                              unsigned short* __restrict__ ALtr,
                                              unsigned short* __restrict__ ASn,
                                              unsigned short* __restrict__ AStr) {
  const float* src = blockIdx.z ? AS : AL;
  unsigned short* dstN = blockIdx.z ? ASn : ALn;
  unsigned short* dstT = blockIdx.z ? AStr : ALtr;
  __shared__ float Xs[64][65];
  const int tid = threadIdx.x;
  const int r0 = blockIdx.x * 64, c0 = blockIdx.y * 64;
  const int lrow = tid >> 4, lc4 = tid & 15;
#pragma unroll
  for (int rr = 0; rr < 4; rr++) {
    int row = rr * 16 + lrow;
    float4 v = *(const float4*)(src + (size_t)(r0 + row) * 1024 + c0 + lc4 * 4);
    Xs[row][lc4 * 4 + 0] = v.x;
    Xs[row][lc4 * 4 + 1] = v.y;
    Xs[row][lc4 * 4 + 2] = v.z;
    Xs[row][lc4 * 4 + 3] = v.w;
    unsigned lo = (unsigned)f2bf(v.x) | ((unsigned)f2bf(v.y) << 16);
    unsigned hi = (unsigned)f2bf(v.z) | ((unsigned)f2bf(v.w) << 16);
    u32x2 pk = {lo, hi};
    *(u32x2*)(dstN + (size_t)(r0 + row) * 1024 + c0 + lc4 * 4) = pk;
  }
  __syncthreads();
  const int wc = tid & 7;
#pragma unroll
  for (int u = 0; u < 2; u++) {
    int t = u * 32 + (tid >> 3);
    unsigned v0 = (unsigned)f2bf(Xs[wc * 8 + 0][t]) | ((unsigned)f2bf(Xs[wc * 8 + 1][t]) << 16);
    unsigned v1 = (unsigned)f2bf(Xs[wc * 8 + 2][t]) | ((unsigned)f2bf(Xs[wc * 8 + 3][t]) << 16);
    unsigned v2 = (unsigned)f2bf(Xs[wc * 8 + 4][t]) | ((unsigned)f2bf(Xs[wc * 8 + 5][t]) << 16);
    unsigned v3 = (unsigned)f2bf(Xs[wc * 8 + 6][t]) | ((unsigned)f2bf(Xs[wc * 8 + 7][t]) << 16);
    u32x4 pk = {v0, v1, v2, v3};
    *(u32x4*)(dstT + (size_t)(c0 + t) * 1024 + r0 + wc * 8) = pk;
  }
}

// ---------------- core 128x128 bf16 GEMM, C = A * Bt^T (pre-GEMMs) ----------
__device__ __forceinline__ void gemm128_bt(const unsigned short* __restrict__ A,
                                           const unsigned short* __restrict__ Bt,
                                           unsigned short* __restrict__ Cp,
                                           int K, size_t ldc, int m0, int n0) {
  __shared__ unsigned short As[128 * 32];
  __shared__ unsigned short Bs[128 * 32];
  const int tid = threadIdx.x;
  const int wave = tid >> 6, lane = tid & 63;
  const int lane15 = lane & 15, quad = lane >> 4;
  const int wm = wave & 1, wn = wave >> 1;
  const int srow = lane >> 2;
  const int schunk = (lane & 3) * 8;

  const unsigned short* gA0 = A + (size_t)(m0 + wave * 16 + srow) * K + schunk;
  const unsigned short* gA1 = A + (size_t)(m0 + 64 + wave * 16 + srow) * K + schunk;
  const unsigned short* gB0 = Bt + (size_t)(n0 + wave * 16 + srow) * K + schunk;
  const unsigned short* gB1 = Bt + (size_t)(n0 + 64 + wave * 16 + srow) * K + schunk;
  unsigned short* lA0 = As + (wave * 16) * 32;
  unsigned short* lA1 = As + (64 + wave * 16) * 32;
  unsigned short* lB0 = Bs + (wave * 16) * 32;
  unsigned short* lB1 = Bs + (64 + wave * 16) * 32;

  f32x4 acc[4][4];
#pragma unroll
  for (int i = 0; i < 4; i++)
#pragma unroll
    for (int j = 0; j < 4; j++) acc[i][j] = (f32x4){0.f, 0.f, 0.f, 0.f};

  const unsigned short* pa = As + (wm * 64 + lane15) * 32 + quad * 8;
  const unsigned short* pb = Bs + (wn * 64 + lane15) * 32 + quad * 8;

  for (int kb = 0; kb < K; kb += 32) {
    __syncthreads();
    __builtin_amdgcn_global_load_lds(
        (const __attribute__((address_space(1))) unsigned int*)(gA0 + kb),
        (__attribute__((address_space(3))) unsigned int*)lA0, 16, 0, 0);
    __builtin_amdgcn_global_load_lds(
        (const __attribute__((address_space(1))) unsigned int*)(gA1 + kb),
        (__attribute__((address_space(3))) unsigned int*)lA1, 16, 0, 0);
    __builtin_amdgcn_global_load_lds(
        (const __attribute__((address_space(1))) unsigned int*)(gB0 + kb),
        (__attribute__((address_space(3))) unsigned int*)lB0, 16, 0, 0);
    __builtin_amdgcn_global_load_lds(
        (const __attribute__((address_space(1))) unsigned int*)(gB1 + kb),
        (__attribute__((address_space(3))) unsigned int*)lB1, 16, 0, 0);
    __syncthreads();

    bf16x8 av[4], bv[4];
#pragma unroll
    for (int mt = 0; mt < 4; mt++) av[mt] = *(const bf16x8*)(pa + mt * 16 * 32);
#pragma unroll
    for (int nt = 0; nt < 4; nt++) bv[nt] = *(const bf16x8*)(pb + nt * 16 * 32);
#pragma unroll
    for (int mt = 0; mt < 4; mt++)
#pragma unroll
      for (int nt = 0; nt < 4; nt++)
        acc[mt][nt] = __builtin_amdgcn_mfma_f32_16x16x32_bf16(av[mt], bv[nt], acc[mt][nt], 0, 0, 0);
  }

#pragma unroll
  for (int mt = 0; mt < 4; mt++) {
#pragma unroll
    for (int nt = 0; nt < 4; nt++) {
      const int col = n0 + wn * 64 + nt * 16 + lane15;
#pragma unroll
      for (int r = 0; r < 4; r++) {
        const int row = m0 + wm * 64 + mt * 16 + quad * 4 + r;
        Cp[(size_t)row * ldc + col] = f2bf(acc[mt][nt][r]);
      }
    }
  }
}

// ---------------- G-precompute GEMMs (batched by z; 5 total) ----------------
__global__ __launch_bounds__(256) void k_gemm_pre(char* ws, int stage) {
  const unsigned short* A;
  const unsigned short* Bt;
  unsigned short* Cp;
  const int z = blockIdx.z;
  unsigned short* ALbf = (unsigned short*)(ws + OFF_ALBF);
  unsigned short* ALt  = (unsigned short*)(ws + OFF_ALT);
  unsigned short* ASbf = (unsigned short*)(ws + OFF_ASBF);
  unsigned short* ASt  = (unsigned short*)(ws + OFF_AST);
  unsigned short* AL2  = (unsigned short*)(ws + OFF_AL2);
  unsigned short* ASAL = (unsigned short*)(ws + OFF_ASAL);
  unsigned short* AS2  = (unsigned short*)(ws + OFF_AS2);
  unsigned short* AL3  = (unsigned short*)(ws + OFF_AL3);
  unsigned short* AS2AL= (unsigned short*)(ws + OFF_AS2AL);
  if (stage == 0) {
    if (z == 0)      { A = ALbf; Bt = ALt;  Cp = AL2;  }   // AL^2
    else if (z == 1) { A = ASbf; Bt = ALt;  Cp = ASAL; }   // AS*AL
    else             { A = ASbf; Bt = ASt;  Cp = AS2;  }   // AS^2
  } else {
    if (z == 0)      { A = AL2;  Bt = ALt;  Cp = AL3;  }   // AL^2*AL = AL^3
    else             { A = AS2;  Bt = ALt;  Cp = AS2AL;}   // AS^2*AL
  }
  gemm128_bt(A, Bt, Cp, 1024, 1024, blockIdx.y * 128, blockIdx.x * 128);
}

// ---------------- assemble Gcat[1024][2048] = [G1 | G2] bf16 (+W cast) ------
__global__ __launch_bounds__(256) void k_assemble_G(const unsigned short* __restrict__ AL2,
                                                    const unsigned short* __restrict__ ASAL,
                                                    const float* __restrict__ ASf,
                                                    const unsigned short* __restrict__ AL3,
                                                    const unsigned short* __restrict__ AS2,
                                                    const unsigned short* __restrict__ AS2AL,
                                                    const float* __restrict__ W,
                                                    unsigned short* __restrict__ Wall,
                                                    unsigned short* __restrict__ G) {
  if (blockIdx.x == 0) {   // fold W -> Wall[g*32+o][c] cast into block 0
    for (int k = threadIdx.x; k < 3072; k += 256) {
      int oo = k >> 5, c = k & 31;
      Wall[k] = f2bf(W[(oo & 31) * 96 + (oo >> 5) * 32 + c]);
    }
  }
  int i = blockIdx.x * 256 + threadIdx.x;           // over 1024*1024
  int r = i >> 10, c = i & 1023;
  float g1 = bf2f(AL2[i]) + ASf[i] - bf2f(ASAL[i]);
  float g2 = bf2f(AL3[i]) + bf2f(AS2[i]) - bf2f(AS2AL[i]);
  G[(size_t)r * 2048 + c]        = f2bf(g1);
  G[(size_t)r * 2048 + 1024 + c] = f2bf(g2);
}

// ---------------- k_mix_g: channel mix via MFMA (K=32) ----------------
// Output Yc[G][j][8] planes, G = og*128 + n8 (j = (b,o,t)).  grid 2048 =
// 16 b x 128 n8 (8 n each), 256 thr / 4 waves (t-quads), XCD-chunked decode.
// Stores: 16B granules, quad = 256B contiguous -> zero write amplification.
__global__ __launch_bounds__(256, 8) void k_mix_g(const float* __restrict__ x,
                                                  const unsigned short* __restrict__ Wall,
                                                  unsigned short* __restrict__ Yc) {
  const int tid = threadIdx.x;
  const int sid = (blockIdx.x & 7) * 256 + (blockIdx.x >> 3);
  const int b   = sid >> 7;
  const int n8g = sid & 127;
  const int nbase = n8g * 8;
  const int wave = tid >> 6, lane = tid & 63;
  const int lane15 = lane & 15, quad = lane >> 4;
  const int t = wave * 16 + lane15;

  bf16x8 afr[6];
#pragma unroll
  for (int ot = 0; ot < 6; ot++)
    afr[ot] = *(const bf16x8*)(Wall + (ot * 16 + lane15) * 32 + quad * 8);

  const float* xb = x + (size_t)b * 2097152 + (size_t)(quad * 8) * 65536 + t;

  bf16x8 bfr[8];
#pragma unroll
  for (int nl = 0; nl < 8; nl++) {
    const float* xp = xb + (size_t)(nbase + nl) * 64;
    unsigned u[4];
#pragma unroll
    for (int e = 0; e < 4; e++) {
      float a  = xp[(size_t)(2 * e) * 65536];
      float c2 = xp[(size_t)(2 * e + 1) * 65536];
      u[e] = (unsigned)f2bf(a) | ((unsigned)f2bf(c2) << 16);
    }
    u32x4 pk = {u[0], u[1], u[2], u[3]};
    bfr[nl] = __builtin_bit_cast(bf16x8, pk);
  }

#pragma unroll
  for (int ot = 0; ot < 6; ot++) {
    f32x4 acc[8];
    const f32x4 z = (f32x4){0.f, 0.f, 0.f, 0.f};
#pragma unroll
    for (int nl = 0; nl < 8; nl++)
      acc[nl] = __builtin_amdgcn_mfma_f32_16x16x32_bf16(afr[ot], bfr[nl], z, 0, 0, 0);
    const int og = ot >> 1;                       // 0:W1x 1:W2x 2:W3x
    const int o  = (ot & 1) * 16 + quad * 4;      // + r
    const size_t plane = (size_t)(og * 128 + n8g) * 262144;
#pragma unroll
    for (int r = 0; r < 4; r++) {
      unsigned u0 = (unsigned)f2bf(acc[0][r]) | ((unsigned)f2bf(acc[1][r]) << 16);
      unsigned u1 = (unsigned)f2bf(acc[2][r]) | ((unsigned)f2bf(acc[3][r]) << 16);
      unsigned u2 = (unsigned)f2bf(acc[4][r]) | ((unsigned)f2bf(acc[5][r]) << 16);
      unsigned u3 = (unsigned)f2bf(acc[6][r]) | ((unsigned)f2bf(acc[7][r]) << 16);
      u32x4 pk = {u0, u1, u2, u3};
      size_t j = (size_t)(b * 32 + o + r) * 64 + t;
      *(u32x4*)(Yc + plane + j * 8) = pk;
    }
  }
}

// ---------------- main GEMM: out = Gcat @ [W2x|W3x]^T + W1x + bias ----------
// M=1024, N=32768, K=2048 (32 K-tiles of BK=64). 512 blocks x 512 thr.
// m201-style phases: {reads+stage BEFORE barrier -> [lgkm(8)] -> barrier ->
// lgkm(0) -> prio1 -> 16 MFMA -> prio0 -> barrier}; stage plan per tile t:
// ph1 A0(t+1), ph2 A1(t+1), ph3 B0(t+2), ph4 B1(t+2); vmcnt(4) at ph4.
__global__ __launch_bounds__(512) void k_gemm_main8(const unsigned short* __restrict__ A,
                                                    const unsigned short* __restrict__ Yc,
                                                    const float* __restrict__ bm,
                                                    float* __restrict__ out) {
  __shared__ unsigned short lds[65536];   // 128 KiB
  const int tid = threadIdx.x;
  const int wave = tid >> 6, lane = tid & 63;
  const int lane15 = lane & 15, quad = lane >> 4;
  const int wr = wave >> 2, wc = wave & 3;          // 2M x 4N

  const int bid = blockIdx.x;
  const int swz = (bid & 7) * 64 + (bid >> 3);      // XCD-bijective (512%8==0)
  const int nx = swz >> 2, my = swz & 3;            // 128 N-tiles x 4 M-tiles
  const int m0 = my * 256, n0 = nx * 256;

  const int srow = tid >> 3;                          // 0..63
  const int cB   = (tid & 7) ^ (srow & 7);            // swizzled k-chunk
  const int skc  = cB << 3;                           // shorts (A path)
  const int ldst0 = (tid & ~63) << 3;                 // shorts, wave-uniform

#define STAGE_A(rowbase, ldsptr, ktile)                                                 \
  do {                                                                                  \
    const unsigned short* _g =                                                          \
        A + (size_t)((rowbase) + srow) * 2048 + (size_t)((ktile) * 64 + skc);           \
    __builtin_amdgcn_global_load_lds(                                                   \
        (const __attribute__((address_space(1))) unsigned int*)_g,                      \
        (__attribute__((address_space(3))) unsigned int*)((ldsptr) + ldst0), 16, 0, 0); \
    __builtin_amdgcn_global_load_lds(                                                   \
        (const __attribute__((address_space(1))) unsigned int*)(_g + 131072),           \
        (__attribute__((address_space(3))) unsigned int*)((ldsptr) + 4096 + ldst0),     \
        16, 0, 0);                                                                      \
  } while (0)

#define STAGE_B(rowbase, ldsptr, ktile)                                                 \
  do {                                                                                  \
    const unsigned short* _g = Yc + (size_t)(128 + (ktile) * 8 + cB) * 262144 +         \
                               (size_t)((rowbase) + srow) * 8;                          \
    __builtin_amdgcn_global_load_lds(                                                   \
        (const __attribute__((address_space(1))) unsigned int*)_g,                      \
        (__attribute__((address_space(3))) unsigned int*)((ldsptr) + ldst0), 16, 0, 0); \
    __builtin_amdgcn_global_load_lds(                                                   \
        (const __attribute__((address_space(1))) unsigned int*)(_g + 512),              \
        (__attribute__((address_space(3))) unsigned int*)((ldsptr) + 4096 + ldst0),     \
        16, 0, 0);                                                                      \
  } while (0)

#define RD_BFR()                                                                        \
  _Pragma("unroll") for (int n = 0; n < 4; n++)                                         \
      _Pragma("unroll") for (int kk = 0; kk < 2; kk++)                                  \
          bfr[n][kk] = *(const bf16x8*)(pB + n * 1024 + aks[kk]);

#define RD_AFR(mA, mB)                                                                  \
  _Pragma("unroll") for (int kk = 0; kk < 2; kk++) {                                    \
    afr[0][kk] = *(const bf16x8*)(pA + (mA) * 1024 + aks[kk]);                          \
    afr[1][kk] = *(const bf16x8*)(pA + (mB) * 1024 + aks[kk]);                          \
  }

#define MFMA2(i0)                                                                       \
  _Pragma("unroll") for (int kk = 0; kk < 2; kk++)                                      \
      _Pragma("unroll") for (int mi = 0; mi < 2; mi++)                                  \
          _Pragma("unroll") for (int n = 0; n < 4; n++)                                 \
              acc[(i0) + mi][n] = __builtin_amdgcn_mfma_f32_16x16x32_bf16(              \
                  afr[mi][kk], bfr[n][kk], acc[(i0) + mi][n], 0, 0, 0);

#define BAR()   asm volatile("" ::: "memory"); __builtin_amdgcn_s_barrier();
#define LGKM0() asm volatile("s_waitcnt lgkmcnt(0)" ::: "memory");                      \
                __builtin_amdgcn_sched_barrier(0);
#define LGKM8() asm volatile("s_waitcnt lgkmcnt(8)" ::: "memory");
#define PRIO1() __builtin_amdgcn_s_setprio(1);
#define PRIO0() __builtin_amdgcn_s_setprio(0);

  unsigned short* Acur = lds;
  unsigned short* Bcur = lds + 16384;
  unsigned short* Aalt = lds + 32768;
  unsigned short* Balt = lds + 49152;

  f32x4 acc[8][4];
#pragma unroll
  for (int i = 0; i < 8; i++)
#pragma unroll
    for (int j = 0; j < 4; j++) acc[i][j] = (f32x4){0.f, 0.f, 0.f, 0.f};

  const int swz8 = (lane15 & 7) << 3;
  int aks[2];
  aks[0] = (quad << 3) ^ swz8;
  aks[1] = (32 | (quad << 3)) ^ swz8;

  bf16x8 bfr[4][2], afr[2][2];

  // ---- prologue: tile0 {A0,A1,B0,B1} + tile1 {B0,B1}; vmcnt(4) => tile0 in ----
  STAGE_A(m0,       Acur,        0);
  STAGE_A(m0 + 128, Acur + 8192, 0);
  STAGE_B(n0,       Bcur,        0);
  STAGE_B(n0 + 128, Bcur + 8192, 0);
  STAGE_B(n0,       Balt,        1);
  STAGE_B(n0 + 128, Balt + 8192, 1);
  asm volatile("s_waitcnt vmcnt(4)" ::: "memory");
  BAR();

  // ---- main loop: tiles 0..29, m201-style 4 phases each ----
  for (int t = 0; t < 30; ++t) {
    const unsigned short* pA = Acur + (wr * 128 + lane15) * 64;
    const unsigned short* pB = Bcur + (wc * 64 + lane15) * 64;
    // ph1: B(t) all + A(t) m01 (12 reads) | stage A0(t+1) -> alt
    RD_BFR();
    RD_AFR(0, 1);
    STAGE_A(m0, Aalt, t + 1);
    LGKM8();
    BAR(); LGKM0();
    PRIO1(); MFMA2(0); PRIO0();
    BAR();
    // ph2: A(t) m23 | stage A1(t+1) -> alt
    RD_AFR(2, 3);
    STAGE_A(m0 + 128, Aalt + 8192, t + 1);
    BAR(); LGKM0();
    PRIO1(); MFMA2(2); PRIO0();
    BAR();
    // ph3: A(t) m45 | stage B0(t+2) -> cur (B(t) reads completed at ph1 MFMA)
    RD_AFR(4, 5);
    STAGE_B(n0, Bcur, t + 2);
    BAR(); LGKM0();
    PRIO1(); MFMA2(4); PRIO0();
    BAR();
    // ph4: A(t) m67 | stage B1(t+2) -> cur ; vmcnt(4) leaves B(t+2) in flight
    RD_AFR(6, 7);
    STAGE_B(n0 + 128, Bcur + 8192, t + 2);
    BAR(); LGKM0();
    PRIO1(); MFMA2(6); PRIO0();
    asm volatile("s_waitcnt vmcnt(4)" ::: "memory");
    BAR();
    unsigned short* tmp;
    tmp = Acur; Acur = Aalt; Aalt = tmp;
    tmp = Bcur; Bcur = Balt; Balt = tmp;
  }

  // ---- tile 30: stage only A(31); end with full drain ----
  {
    const unsigned short* pA = Acur + (wr * 128 + lane15) * 64;
    const unsigned short* pB = Bcur + (wc * 64 + lane15) * 64;
    RD_BFR();
    RD_AFR(0, 1);
    STAGE_A(m0, Aalt, 31);
    LGKM8();
    BAR(); LGKM0();
    PRIO1(); MFMA2(0); PRIO0();
    BAR();
    RD_AFR(2, 3);
    STAGE_A(m0 + 128, Aalt + 8192, 31);
    BAR(); LGKM0();
    PRIO1(); MFMA2(2); PRIO0();
    BAR();
    RD_AFR(4, 5);
    BAR(); LGKM0();
    PRIO1(); MFMA2(4); PRIO0();
    BAR();
    RD_AFR(6, 7);
    BAR(); LGKM0();
    PRIO1(); MFMA2(6); PRIO0();
    asm volatile("s_waitcnt vmcnt(0)" ::: "memory");
    BAR();
    unsigned short* tmp;
    tmp = Acur; Acur = Aalt; Aalt = tmp;
    tmp = Bcur; Bcur = Balt; Balt = tmp;
  }

  // ---- tile 31: pure compute (no stages, no trailing sync) ----
  {
    const unsigned short* pA = Acur + (wr * 128 + lane15) * 64;
    const unsigned short* pB = Bcur + (wc * 64 + lane15) * 64;
    RD_BFR();
#pragma unroll
    for (int p = 0; p < 4; p++) {
      RD_AFR(2 * p, 2 * p + 1);
      LGKM0();
      MFMA2(2 * p);
    }
  }

  // ---- fused epilogue: out[b,o,n',t] = acc + W1x + bias (fp32 store) ----
#pragma unroll
  for (int mt = 0; mt < 8; mt++) {
    const int row = m0 + wr * 128 + mt * 16 + quad * 4;
#pragma unroll
    for (int nf = 0; nf < 4; nf++) {
      const int col = n0 + wc * 64 + nf * 16 + lane15;
      const int bo_idx = col >> 6;                    // b*32+o (uniform)
      const float bo = bm[bo_idx & 31];
      const size_t obase = (size_t)bo_idx * 65536 + (col & 63);
      ushort4 yv = *(const ushort4*)(Yc + (size_t)(row >> 3) * 262144 +
                                     (size_t)col * 8 + (row & 7));
      out[obase + (size_t)(row + 0) * 64] = acc[mt][nf][0] + bf2f(yv.x) + bo;
      out[obase + (size_t)(row + 1) * 64] = acc[mt][nf][1] + bf2f(yv.y) + bo;
      out[obase + (size_t)(row + 2) * 64] = acc[mt][nf][2] + bf2f(yv.z) + bo;
      out[obase + (size_t)(row + 3) * 64] = acc[mt][nf][3] + bf2f(yv.w) + bo;
    }
  }
#undef STAGE_A
#undef STAGE_B
#undef RD_BFR
#undef RD_AFR
#undef MFMA2
#undef BAR
#undef LGKM0
#undef LGKM8
#undef PRIO1
#undef PRIO0
}

extern "C" void kernel_launch(void* const* d_in, const int* in_sizes, int n_in,
                              void* d_out, int out_size, void* d_ws, size_t ws_size,
                              hipStream_t stream) {
  const float* x  = (const float*)d_in[0];
  const float* AL = (const float*)d_in[1];
  const float* AS = (const float*)d_in[2];
  const float* W  = (const float*)d_in[3];
  const float* bm = (const float*)d_in[4];
  float* out = (float*)d_out;
  char* ws = (char*)d_ws;

  unsigned short* Yc    = (unsigned short*)(ws + OFF_YC);
  unsigned short* ALbf  = (unsigned short*)(ws + OFF_ALBF);
  unsigned short* ALt   = (unsigned short*)(ws + OFF_ALT);
  unsigned short* ASbf  = (unsigned short*)(ws + OFF_ASBF);
  unsigned short* ASt   = (unsigned short*)(ws + OFF_AST);
  unsigned short* AL2   = (unsigned short*)(ws + OFF_AL2);
  unsigned short* ASAL  = (unsigned short*)(ws + OFF_ASAL);
  unsigned short* AS2   = (unsigned short*)(ws + OFF_AS2);
  unsigned short* AL3   = (unsigned short*)(ws + OFF_AL3);
  unsigned short* AS2AL = (unsigned short*)(ws + OFF_AS2AL);
  unsigned short* Gm    = (unsigned short*)(ws + OFF_G);
  unsigned short* Wall  = (unsigned short*)(ws + OFF_ALBF);  // reused after stage0

  // 1) AL/AS -> bf16 natural + transposed (merged, z = which matrix)
  k_prep<<<dim3(16, 16, 2), 256, 0, stream>>>(AL, AS, ALbf, ALt, ASbf, ASt);
  // 2) G pieces: {AL2, ASAL, AS2} then {AL3, AS2AL}
  k_gemm_pre<<<dim3(8, 8, 3), 256, 0, stream>>>(ws, 0);
  k_gemm_pre<<<dim3(8, 8, 2), 256, 0, stream>>>(ws, 1);
  // 3) assemble Gcat (+ W -> Wall cast folded into block 0)
  k_assemble_G<<<4096, 256, 0, stream>>>(AL2, ASAL, AS, AL3, AS2, AS2AL, W, Wall, Gm);
  // 4) channel mix: x -> Yc planes [W1x | W2x | W3x]
  k_mix_g<<<2048, 256, 0, stream>>>(x, Wall, Yc);
  // 5) fused graph GEMM + epilogue: out = Gcat @ [W2x|W3x]^T + W1x + bias
  k_gemm_main8<<<dim3(512, 1, 1), 512, 0, stream>>>(Gm, Yc, bm, out);
}